// Round 6
// baseline (254.727 us; speedup 1.0000x reference)
//
#include <hip/hip_runtime.h>
#include <math.h>

#define HW 16384
#define CC 64
#define HID 128
#define EPSV 1e-5f
#define ROW 36     // padded LDS row for 32-pixel tiles (36%32=4 -> bank shift)
#define QROW 205   // padded per-pixel row for qkv staging (192 + 13, odd)
#define HDSTR 131072    // per-head stride: 32*32*16*8 floats
#define NBLK 512

// q/k/v layout: [head][(hs*32+ws)*16 + sub][8], sub = (h&3)*4 + (w&3)

// Shared-memory union across the three phases
struct SA {
    float xs[CC][ROW];
    float qk[32][QROW];
    float mu1[32], rs1[32], muq[32], rsq[32], muk[32], rsk[32];
};
struct SB {
    float kt[4][15][33][2];
    float vt[4][15][33][2];
};
struct SC {
    float xres[CC][ROW];
    float tb[CC][ROW];
    float h1[HID][ROW];
    float mu[32], rs[32];
};
union SU {
    SA a;
    SB b;
    SC c;
};

// Manual persistent-grid barrier: works under graph replay (no cooperative API).
// Counter is cumulative per launch (target 512, then 1024); re-zeroed by the
// pre-launch hipMemsetAsync on every graph replay. __threadfence() both sides
// gives device-scope release/acquire (cross-XCD L2 visibility, Guideline 16).
__device__ __forceinline__ void grid_barrier(unsigned* bar, unsigned target) {
    __syncthreads();
    if (threadIdx.x == 0) {
        __threadfence();                 // release: make this block's writes visible
        atomicAdd(bar, 1u);              // device-scope RMW
        unsigned v;
        do {
            __builtin_amdgcn_s_sleep(2);
            v = __hip_atomic_load(bar, __ATOMIC_RELAXED, __HIP_MEMORY_SCOPE_AGENT);
        } while (v < target);
        __threadfence();                 // acquire: invalidate stale cache
    }
    __syncthreads();
}

// Fused persistent kernel: phase A (ln1->qkv->q/k LN), barrier,
// phase B (NAT attention), barrier, phase C (proj+res->ln2->mlp->out).
// 512 blocks x 256 thr: LDS 36.3KB -> 4 blk/CU; launch_bounds(256,2) -> VGPR<=256
// -> 2 blk/CU; 512 = 2x256CU -> all blocks co-resident (barrier is safe).
__global__ __launch_bounds__(256, 2) void k_fused(
    const float* __restrict__ x,
    const float* __restrict__ n1w, const float* __restrict__ n1b,
    const float* __restrict__ qkvw, const float* __restrict__ qkvb,
    const float* __restrict__ qnw, const float* __restrict__ qnb,
    const float* __restrict__ knw, const float* __restrict__ knb,
    const float* __restrict__ pw, const float* __restrict__ pb,
    const float* __restrict__ g1,
    const float* __restrict__ n2w, const float* __restrict__ n2b,
    const float* __restrict__ f1w, const float* __restrict__ f1b,
    const float* __restrict__ mnw, const float* __restrict__ mnb,
    const float* __restrict__ f2w, const float* __restrict__ f2b,
    const float* __restrict__ g2,
    float* __restrict__ qo, float* __restrict__ ko, float* __restrict__ vo,
    float* __restrict__ oatt,
    float* __restrict__ out,
    unsigned* bar)
{
    __shared__ __align__(16) SU sm;
    const int t = threadIdx.x;
    const int bid = blockIdx.x;

    // ================= Phase A: ln1 -> qkv (all 192) -> q/k LN -> ws =================
    {
        const int pix0 = bid * 32;
        auto& xs = sm.a.xs;
        auto& qk = sm.a.qk;

        {
            const int c = t >> 2, pxq = (t & 3) * 8;
            *(float4*)&xs[c][pxq]     = *(const float4*)(x + c * HW + pix0 + pxq);
            *(float4*)&xs[c][pxq + 4] = *(const float4*)(x + c * HW + pix0 + pxq + 4);
        }
        __syncthreads();

        // ln1 stats: waves 0,1 each cover 16 px (4 partials x 16 px)
        if (t < 128) {
            const int px = ((t >> 6) << 4) + (t & 15);
            const int part = (t & 63) >> 4;
            float s = 0.f, ss = 0.f;
            #pragma unroll
            for (int i = 0; i < 16; ++i) { float v = xs[part * 16 + i][px]; s += v; ss += v * v; }
            s += __shfl_xor(s, 16); ss += __shfl_xor(ss, 16);
            s += __shfl_xor(s, 32); ss += __shfl_xor(ss, 32);
            if (part == 0) {
                float m = s * (1.f / CC);
                sm.a.mu1[px] = m;
                sm.a.rs1[px] = rsqrtf(ss * (1.f / CC) - m * m + EPSV);
            }
        }
        __syncthreads();

        // apply ln1 in-place
        {
            const int c = t >> 2, pxq = (t & 3) * 8;
            const float wgt = n1w[c], bia = n1b[c];
            #pragma unroll
            for (int hh = 0; hh < 2; ++hh) {
                float4 v = *(float4*)&xs[c][pxq + hh * 4];
                float4 m4 = *(float4*)&sm.a.mu1[pxq + hh * 4];
                float4 r4 = *(float4*)&sm.a.rs1[pxq + hh * 4];
                v.x = (v.x - m4.x) * r4.x * wgt + bia;
                v.y = (v.y - m4.y) * r4.y * wgt + bia;
                v.z = (v.z - m4.z) * r4.z * wgt + bia;
                v.w = (v.w - m4.w) * r4.w * wgt + bia;
                *(float4*)&xs[c][pxq + hh * 4] = v;
            }
        }
        __syncthreads();

        // qkv matvec: thread = (og 0..31 -> 6 outs, pxg 0..7 -> 4 px)
        {
            const int o0 = (t >> 3) * 6;
            const int px0 = (t & 7) * 4;
            float a[6][4];
            #pragma unroll
            for (int j = 0; j < 6; ++j) {
                float b = qkvb[o0 + j];
                a[j][0] = b; a[j][1] = b; a[j][2] = b; a[j][3] = b;
            }
            for (int c = 0; c < CC; c += 4) {
                float4 xv[4];
                #pragma unroll
                for (int i = 0; i < 4; ++i) xv[i] = *(float4*)&xs[c + i][px0];
                #pragma unroll
                for (int j = 0; j < 6; ++j) {
                    float4 wv = *(const float4*)(qkvw + (o0 + j) * CC + c);
                    #pragma unroll
                    for (int pp = 0; pp < 4; ++pp) {
                        a[j][pp] += wv.x * (&xv[0].x)[pp] + wv.y * (&xv[1].x)[pp]
                                  + wv.z * (&xv[2].x)[pp] + wv.w * (&xv[3].x)[pp];
                    }
                }
            }
            #pragma unroll
            for (int j = 0; j < 6; ++j) {
                #pragma unroll
                for (int pp = 0; pp < 4; ++pp) qk[px0 + pp][o0 + j] = a[j][pp];
            }
        }
        __syncthreads();

        // q stats (waves 0,1) and k stats (waves 2,3)
        if (t < 128) {
            const int px = ((t >> 6) << 4) + (t & 15);
            const int part = (t & 63) >> 4;
            float s = 0.f, ss = 0.f;
            #pragma unroll
            for (int i = 0; i < 16; ++i) { float v = qk[px][part * 16 + i]; s += v; ss += v * v; }
            s += __shfl_xor(s, 16); ss += __shfl_xor(ss, 16);
            s += __shfl_xor(s, 32); ss += __shfl_xor(ss, 32);
            if (part == 0) {
                float m = s * (1.f / CC);
                sm.a.muq[px] = m;
                sm.a.rsq[px] = rsqrtf(ss * (1.f / CC) - m * m + EPSV);
            }
        } else {
            const int t2 = t - 128;
            const int px = ((t2 >> 6) << 4) + (t2 & 15);
            const int part = (t2 & 63) >> 4;
            float s = 0.f, ss = 0.f;
            #pragma unroll
            for (int i = 0; i < 16; ++i) { float v = qk[px][CC + part * 16 + i]; s += v; ss += v * v; }
            s += __shfl_xor(s, 16); ss += __shfl_xor(ss, 16);
            s += __shfl_xor(s, 32); ss += __shfl_xor(ss, 32);
            if (part == 0) {
                float m = s * (1.f / CC);
                sm.a.muk[px] = m;
                sm.a.rsk[px] = rsqrtf(ss * (1.f / CC) - m * m + EPSV);
            }
        }
        __syncthreads();

        // write q (LN), k (LN), v to interleaved subgrid layout
        #pragma unroll
        for (int pass = 0; pass < 2; ++pass) {
            const int px = (t >> 4) + pass * 16;
            const int cg2 = t & 15;
            const int c = cg2 * 4;
            const int hd = cg2 >> 1;
            const int d4 = (cg2 & 1) * 4;
            const int pixel = pix0 + px;
            const int h = pixel >> 7, w = pixel & 127;
            const int pos = ((h >> 2) * 32 + (w >> 2)) * 16 + (h & 3) * 4 + (w & 3);
            const int gbase = hd * HDSTR + pos * 8 + d4;

            const float mq = sm.a.muq[px], rq = sm.a.rsq[px];
            float4 qv = *(float4*)&qk[px][c];
            float4 qw = *(const float4*)(qnw + c);
            float4 qb = *(const float4*)(qnb + c);
            qv.x = (qv.x - mq) * rq * qw.x + qb.x;
            qv.y = (qv.y - mq) * rq * qw.y + qb.y;
            qv.z = (qv.z - mq) * rq * qw.z + qb.z;
            qv.w = (qv.w - mq) * rq * qw.w + qb.w;
            *(float4*)(qo + gbase) = qv;

            const float mk = sm.a.muk[px], rk = sm.a.rsk[px];
            float4 kv = *(float4*)&qk[px][CC + c];
            float4 kw = *(const float4*)(knw + c);
            float4 kb = *(const float4*)(knb + c);
            kv.x = (kv.x - mk) * rk * kw.x + kb.x;
            kv.y = (kv.y - mk) * rk * kw.y + kb.y;
            kv.z = (kv.z - mk) * rk * kw.z + kb.z;
            kv.w = (kv.w - mk) * rk * kw.w + kb.w;
            *(float4*)(ko + gbase) = kv;

            float4 vv = *(float4*)&qk[px][2 * CC + c];
            *(float4*)(vo + gbase) = vv;
        }
    }

    grid_barrier(bar, NBLK);

    // ================= Phase B: subgrid NAT via LDS tiles =================
    {
        const int band = bid & 3;
        const int sub  = (bid >> 2) & 15;
        const int head = bid >> 6;
        const int hs0 = band * 8;

        auto& kt = sm.b.kt;
        auto& vt = sm.b.vt;

        const float* kb = ko + head * HDSTR;
        const float* vb = vo + head * HDSTR;

        // stage k/v subgrid rows hs0-4 .. hs0+10 (clamped): 15 rows x 32 cols x 8 ch
        for (int idx = t; idx < 960; idx += 256) {
            const int row = idx >> 6;
            const int rem = idx & 63;
            const int wsc = rem >> 1;
            const int dh = rem & 1;
            int gr = hs0 - 4 + row;
            gr = gr < 0 ? 0 : (gr > 31 ? 31 : gr);
            const int gaddr = ((gr * 32 + wsc) * 16 + sub) * 8 + dh * 4;
            const float4 kv4 = *(const float4*)(kb + gaddr);
            const float4 vv4 = *(const float4*)(vb + gaddr);
            const int dp = dh * 2;
            kt[dp][row][wsc][0] = kv4.x;     kt[dp][row][wsc][1] = kv4.y;
            kt[dp + 1][row][wsc][0] = kv4.z; kt[dp + 1][row][wsc][1] = kv4.w;
            vt[dp][row][wsc][0] = vv4.x;     vt[dp][row][wsc][1] = vv4.y;
            vt[dp + 1][row][wsc][0] = vv4.z; vt[dp + 1][row][wsc][1] = vv4.w;
        }

        const int r = t >> 5;        // 0..7
        const int wsc = t & 31;      // 0..31
        const int hs = hs0 + r;

        const float* qp = qo + head * HDSTR + ((hs * 32 + wsc) * 16 + sub) * 8;
        const float4 q0 = *(const float4*)qp;
        const float4 q1 = *(const float4*)(qp + 4);
        const float scale = 0.35355339059327373f;   // 8^-0.5

        __syncthreads();

        // ---- pass 1: all 64 scores into registers; 4-way parallel max ----
        float s[64];
        float mx0 = -1e30f, mx1 = -1e30f, mx2 = -1e30f, mx3 = -1e30f;
        #pragma unroll
        for (int i = 0; i < 8; ++i) {
            const int lr = r + i;                               // LDS row 0..14
            const bool vh = (unsigned)(hs + i - 4) < 32u;
            #pragma unroll
            for (int j = 0; j < 8; ++j) {
                const int cs = wsc + j - 4;
                const bool valid = vh && ((unsigned)cs < 32u);
                const int cc = cs < 0 ? 0 : (cs > 31 ? 31 : cs);
                const float2 kA = *(const float2*)&kt[0][lr][cc][0];
                const float2 kB = *(const float2*)&kt[1][lr][cc][0];
                const float2 kC = *(const float2*)&kt[2][lr][cc][0];
                const float2 kD = *(const float2*)&kt[3][lr][cc][0];
                float sv = q0.x * kA.x + q0.y * kA.y + q0.z * kB.x + q0.w * kB.y
                         + q1.x * kC.x + q1.y * kC.y + q1.z * kD.x + q1.w * kD.y;
                sv *= scale;
                sv = valid ? sv : -INFINITY;
                s[i * 8 + j] = sv;
                if ((j & 3) == 0)      mx0 = fmaxf(mx0, sv);
                else if ((j & 3) == 1) mx1 = fmaxf(mx1, sv);
                else if ((j & 3) == 2) mx2 = fmaxf(mx2, sv);
                else                   mx3 = fmaxf(mx3, sv);
            }
        }
        const float mx = fmaxf(fmaxf(mx0, mx1), fmaxf(mx2, mx3));

        // ---- pass 2: exp + PV accumulate (no rescale; masked taps give p=0) ----
        float l = 0.f;
        float a0 = 0.f, a1 = 0.f, a2 = 0.f, a3 = 0.f, a4 = 0.f, a5 = 0.f, a6 = 0.f, a7 = 0.f;
        #pragma unroll
        for (int i = 0; i < 8; ++i) {
            const int lr = r + i;
            #pragma unroll
            for (int j = 0; j < 8; ++j) {
                const int cs = wsc + j - 4;
                const int cc = cs < 0 ? 0 : (cs > 31 ? 31 : cs);
                const float p = __expf(s[i * 8 + j] - mx);
                const float2 vA = *(const float2*)&vt[0][lr][cc][0];
                const float2 vB = *(const float2*)&vt[1][lr][cc][0];
                const float2 vC = *(const float2*)&vt[2][lr][cc][0];
                const float2 vD = *(const float2*)&vt[3][lr][cc][0];
                l += p;
                a0 += p * vA.x;  a1 += p * vA.y;
                a2 += p * vB.x;  a3 += p * vB.y;
                a4 += p * vC.x;  a5 += p * vC.y;
                a6 += p * vD.x;  a7 += p * vD.y;
            }
        }

        const float inv = 1.f / l;
        const int a = sub >> 2, b = sub & 3;
        const int h = hs * 4 + a, w = wsc * 4 + b;
        float* op = oatt + (h * 128 + w) * 64 + head * 8;
        float4 r0 = {a0 * inv, a1 * inv, a2 * inv, a3 * inv};
        float4 r1 = {a4 * inv, a5 * inv, a6 * inv, a7 * inv};
        *(float4*)op = r0;
        *(float4*)(op + 4) = r1;
    }

    grid_barrier(bar, 2 * NBLK);

    // ================= Phase C: proj+res -> ln2 -> fc1 -> mnLN+silu -> fc2 -> out ====
    {
        const int pix0 = bid * 32;
        auto& xres = sm.c.xres;
        auto& tb = sm.c.tb;
        auto& h1 = sm.c.h1;

        {
            const int c = t >> 2, pxq = (t & 3) * 8;
            *(float4*)&xres[c][pxq]     = *(const float4*)(x + c * HW + pix0 + pxq);
            *(float4*)&xres[c][pxq + 4] = *(const float4*)(x + c * HW + pix0 + pxq + 4);
        }
        #pragma unroll
        for (int pass = 0; pass < 2; ++pass) {
            const int px = (t >> 4) + pass * 16, cg2 = (t & 15) * 4;
            float4 ov = *(const float4*)(oatt + (pix0 + px) * CC + cg2);
            tb[cg2][px] = ov.x; tb[cg2 + 1][px] = ov.y; tb[cg2 + 2][px] = ov.z; tb[cg2 + 3][px] = ov.w;
        }
        __syncthreads();

        // proj (64x64) + gamma1 residual into xres
        {
            const int o0 = (t >> 3) * 2;
            const int px0 = (t & 7) * 4;
            float a[2][4];
            #pragma unroll
            for (int j = 0; j < 2; ++j) {
                float b = pb[o0 + j];
                a[j][0] = b; a[j][1] = b; a[j][2] = b; a[j][3] = b;
            }
            for (int c = 0; c < CC; c += 4) {
                float4 xv[4];
                #pragma unroll
                for (int i = 0; i < 4; ++i) xv[i] = *(float4*)&tb[c + i][px0];
                #pragma unroll
                for (int j = 0; j < 2; ++j) {
                    float4 wv = *(const float4*)(pw + (o0 + j) * CC + c);
                    #pragma unroll
                    for (int pp = 0; pp < 4; ++pp) {
                        a[j][pp] += wv.x * (&xv[0].x)[pp] + wv.y * (&xv[1].x)[pp]
                                  + wv.z * (&xv[2].x)[pp] + wv.w * (&xv[3].x)[pp];
                    }
                }
            }
            #pragma unroll
            for (int j = 0; j < 2; ++j) {
                const float gg = g1[o0 + j];
                #pragma unroll
                for (int pp = 0; pp < 4; ++pp) xres[o0 + j][px0 + pp] += gg * a[j][pp];
            }
        }
        __syncthreads();

        // ln2 stats (waves 0,1)
        if (t < 128) {
            const int px = ((t >> 6) << 4) + (t & 15);
            const int part = (t & 63) >> 4;
            float s = 0.f, ss = 0.f;
            #pragma unroll
            for (int i = 0; i < 16; ++i) { float v = xres[part * 16 + i][px]; s += v; ss += v * v; }
            s += __shfl_xor(s, 16); ss += __shfl_xor(ss, 16);
            s += __shfl_xor(s, 32); ss += __shfl_xor(ss, 32);
            if (part == 0) {
                float m = s * (1.f / CC);
                sm.c.mu[px] = m;
                sm.c.rs[px] = rsqrtf(ss * (1.f / CC) - m * m + EPSV);
            }
        }
        __syncthreads();

        // apply ln2 -> tb
        {
            const int c = t >> 2, pxq = (t & 3) * 8;
            const float wgt = n2w[c], bia = n2b[c];
            #pragma unroll
            for (int hh = 0; hh < 2; ++hh) {
                float4 v = *(float4*)&xres[c][pxq + hh * 4];
                float4 m4 = *(float4*)&sm.c.mu[pxq + hh * 4];
                float4 r4 = *(float4*)&sm.c.rs[pxq + hh * 4];
                v.x = (v.x - m4.x) * r4.x * wgt + bia;
                v.y = (v.y - m4.y) * r4.y * wgt + bia;
                v.z = (v.z - m4.z) * r4.z * wgt + bia;
                v.w = (v.w - m4.w) * r4.w * wgt + bia;
                *(float4*)&tb[c][pxq + hh * 4] = v;
            }
        }
        __syncthreads();

        // fc1 (128x64) -> h1
        {
            const int o0 = (t >> 3) * 4;
            const int px0 = (t & 7) * 4;
            float a[4][4];
            #pragma unroll
            for (int j = 0; j < 4; ++j) {
                float b = f1b[o0 + j];
                a[j][0] = b; a[j][1] = b; a[j][2] = b; a[j][3] = b;
            }
            for (int c = 0; c < CC; c += 4) {
                float4 xv[4];
                #pragma unroll
                for (int i = 0; i < 4; ++i) xv[i] = *(float4*)&tb[c + i][px0];
                #pragma unroll
                for (int j = 0; j < 4; ++j) {
                    float4 wv = *(const float4*)(f1w + (o0 + j) * CC + c);
                    #pragma unroll
                    for (int pp = 0; pp < 4; ++pp) {
                        a[j][pp] += wv.x * (&xv[0].x)[pp] + wv.y * (&xv[1].x)[pp]
                                  + wv.z * (&xv[2].x)[pp] + wv.w * (&xv[3].x)[pp];
                    }
                }
            }
            #pragma unroll
            for (int j = 0; j < 4; ++j) {
                #pragma unroll
                for (int pp = 0; pp < 4; ++pp) h1[o0 + j][px0 + pp] = a[j][pp];
            }
        }
        __syncthreads();

        // mn stats over 128 channels (waves 0,1)
        if (t < 128) {
            const int px = ((t >> 6) << 4) + (t & 15);
            const int part = (t & 63) >> 4;
            float s = 0.f, ss = 0.f;
            #pragma unroll
            for (int i = 0; i < 32; ++i) { float v = h1[part * 32 + i][px]; s += v; ss += v * v; }
            s += __shfl_xor(s, 16); ss += __shfl_xor(ss, 16);
            s += __shfl_xor(s, 32); ss += __shfl_xor(ss, 32);
            if (part == 0) {
                float m = s * (1.f / HID);
                sm.c.mu[px] = m;
                sm.c.rs[px] = rsqrtf(ss * (1.f / HID) - m * m + EPSV);
            }
        }
        __syncthreads();

        // apply mn LN + silu in-place
        {
            const int c = t >> 1, ph = (t & 1) * 16;
            const float wgt = mnw[c], bia = mnb[c];
            #pragma unroll
            for (int qq = 0; qq < 4; ++qq) {
                float4 v = *(float4*)&h1[c][ph + qq * 4];
                float4 m4 = *(float4*)&sm.c.mu[ph + qq * 4];
                float4 r4 = *(float4*)&sm.c.rs[ph + qq * 4];
                float hv;
                hv = (v.x - m4.x) * r4.x * wgt + bia; v.x = hv / (1.f + __expf(-hv));
                hv = (v.y - m4.y) * r4.y * wgt + bia; v.y = hv / (1.f + __expf(-hv));
                hv = (v.z - m4.z) * r4.z * wgt + bia; v.z = hv / (1.f + __expf(-hv));
                hv = (v.w - m4.w) * r4.w * wgt + bia; v.w = hv / (1.f + __expf(-hv));
                *(float4*)&h1[c][ph + qq * 4] = v;
            }
        }
        __syncthreads();

        // fc2 (64x128) + gamma2 residual -> out (float4 stores)
        {
            const int o0 = (t >> 3) * 2;
            const int px0 = (t & 7) * 4;
            float a[2][4];
            #pragma unroll
            for (int j = 0; j < 2; ++j) {
                float b = f2b[o0 + j];
                a[j][0] = b; a[j][1] = b; a[j][2] = b; a[j][3] = b;
            }
            for (int c = 0; c < HID; c += 4) {
                float4 xv[4];
                #pragma unroll
                for (int i = 0; i < 4; ++i) xv[i] = *(float4*)&h1[c + i][px0];
                #pragma unroll
                for (int j = 0; j < 2; ++j) {
                    float4 wv = *(const float4*)(f2w + (o0 + j) * HID + c);
                    #pragma unroll
                    for (int pp = 0; pp < 4; ++pp) {
                        a[j][pp] += wv.x * (&xv[0].x)[pp] + wv.y * (&xv[1].x)[pp]
                                  + wv.z * (&xv[2].x)[pp] + wv.w * (&xv[3].x)[pp];
                    }
                }
            }
            #pragma unroll
            for (int j = 0; j < 2; ++j) {
                const float gg = g2[o0 + j];
                float4 xr = *(float4*)&xres[o0 + j][px0];
                float4 ov = {xr.x + gg * a[j][0], xr.y + gg * a[j][1],
                             xr.z + gg * a[j][2], xr.w + gg * a[j][3]};
                *(float4*)(out + (o0 + j) * HW + pix0 + px0) = ov;
            }
        }
    }
}

extern "C" void kernel_launch(void* const* d_in, const int* in_sizes, int n_in,
                              void* d_out, int out_size, void* d_ws, size_t ws_size,
                              hipStream_t stream) {
    (void)in_sizes; (void)n_in; (void)out_size; (void)ws_size;
    const float* x      = (const float*)d_in[0];
    const float* n1w    = (const float*)d_in[1];
    const float* n1b    = (const float*)d_in[2];
    const float* qkvw   = (const float*)d_in[3];
    const float* qkvb   = (const float*)d_in[4];
    const float* qnw    = (const float*)d_in[5];
    const float* qnb    = (const float*)d_in[6];
    const float* knw    = (const float*)d_in[7];
    const float* knb    = (const float*)d_in[8];
    const float* pw     = (const float*)d_in[9];
    const float* pb     = (const float*)d_in[10];
    const float* g1     = (const float*)d_in[11];
    const float* n2w    = (const float*)d_in[12];
    const float* n2b    = (const float*)d_in[13];
    const float* f1w    = (const float*)d_in[14];
    const float* f1b    = (const float*)d_in[15];
    const float* mnw    = (const float*)d_in[16];
    const float* mnb    = (const float*)d_in[17];
    const float* f2w    = (const float*)d_in[18];
    const float* f2b    = (const float*)d_in[19];
    const float* g2     = (const float*)d_in[20];
    float* out = (float*)d_out;

    float* ws = (float*)d_ws;
    const size_t CHW = (size_t)CC * HW;   // 1,048,576 floats
    float* qo   = ws;
    float* ko   = ws + CHW;
    float* vo   = ws + 2 * CHW;
    float* oatt = ws + 3 * CHW;
    unsigned* bar = (unsigned*)(ws + 4 * CHW);

    // zero the barrier counter (stream-ordered; replays with the graph)
    hipMemsetAsync((void*)bar, 0, 64, stream);

    k_fused<<<dim3(NBLK), dim3(256), 0, stream>>>(
        x, n1w, n1b, qkvw, qkvb, qnw, qnb, knw, knb,
        pw, pb, g1, n2w, n2b, f1w, f1b, mnw, mnb, f2w, f2b, g2,
        qo, ko, vo, oatt, out, bar);
}

// Round 7
// 135.801 us; speedup vs baseline: 1.8757x; 1.8757x over previous
//
#include <hip/hip_runtime.h>
#include <math.h>

#define HW 16384
#define CC 64
#define HID 128
#define EPSV 1e-5f
#define ROW 36     // padded LDS row for 32-pixel fp32 tiles
#define SROW 69    // padded per-pixel row for single-branch staging (64 + 5, odd)
#define HDSTR 131072    // per-head stride: 32*32*16*8 floats

typedef __attribute__((ext_vector_type(8))) short bf16x8;   // 8 bf16 = 4 VGPRs (guide-verified)
typedef __attribute__((ext_vector_type(4))) float f32x4v;   // MFMA accumulator

__device__ __forceinline__ unsigned short f2bf(float f) {   // RNE fp32->bf16
    unsigned u = __float_as_uint(f);
    u += 0x7FFFu + ((u >> 16) & 1u);
    return (unsigned short)(u >> 16);
}
__device__ __forceinline__ unsigned pack2bf(float a, float b) {
    return (unsigned)f2bf(a) | ((unsigned)f2bf(b) << 16);
}

// q/k/v layout: [head][(hs*32+ws)*16 + sub][8], sub = (h&3)*4 + (w&3)

// ---------------- Kernel A: ln1 -> one of {q,k,v} matvec -> LN -> ws ----------------
// grid.y = sel: 0=q, 1=k, 2=v (r3-verified body).
__global__ __launch_bounds__(256) void k_ln_qkv(
    const float* __restrict__ x,
    const float* __restrict__ n1w, const float* __restrict__ n1b,
    const float* __restrict__ qkvw, const float* __restrict__ qkvb,
    const float* __restrict__ qnw, const float* __restrict__ qnb,
    const float* __restrict__ knw, const float* __restrict__ knb,
    float* __restrict__ qo, float* __restrict__ ko, float* __restrict__ vo)
{
    __shared__ __align__(16) float xs[CC][ROW];
    __shared__ __align__(16) float qk[32][SROW];
    __shared__ __align__(16) float mu1[32], rs1[32], mu2[32], rs2[32];

    const int t = threadIdx.x;
    const int pix0 = blockIdx.x * 32;
    const int sel = blockIdx.y;

    {
        const int c = t >> 2, pxq = (t & 3) * 8;
        *(float4*)&xs[c][pxq]     = *(const float4*)(x + c * HW + pix0 + pxq);
        *(float4*)&xs[c][pxq + 4] = *(const float4*)(x + c * HW + pix0 + pxq + 4);
    }
    __syncthreads();

    if (t < 128) {
        const int px = ((t >> 6) << 4) + (t & 15);
        const int part = (t & 63) >> 4;
        float s = 0.f, ss = 0.f;
        #pragma unroll
        for (int i = 0; i < 16; ++i) { float v = xs[part * 16 + i][px]; s += v; ss += v * v; }
        s += __shfl_xor(s, 16); ss += __shfl_xor(ss, 16);
        s += __shfl_xor(s, 32); ss += __shfl_xor(ss, 32);
        if (part == 0) {
            float m = s * (1.f / CC);
            mu1[px] = m;
            rs1[px] = rsqrtf(ss * (1.f / CC) - m * m + EPSV);
        }
    }
    __syncthreads();

    {
        const int c = t >> 2, pxq = (t & 3) * 8;
        const float wgt = n1w[c], bia = n1b[c];
        #pragma unroll
        for (int hh = 0; hh < 2; ++hh) {
            float4 v = *(float4*)&xs[c][pxq + hh * 4];
            float4 m4 = *(float4*)&mu1[pxq + hh * 4];
            float4 r4 = *(float4*)&rs1[pxq + hh * 4];
            v.x = (v.x - m4.x) * r4.x * wgt + bia;
            v.y = (v.y - m4.y) * r4.y * wgt + bia;
            v.z = (v.z - m4.z) * r4.z * wgt + bia;
            v.w = (v.w - m4.w) * r4.w * wgt + bia;
            *(float4*)&xs[c][pxq + hh * 4] = v;
        }
    }
    __syncthreads();

    {
        const int o0 = (t >> 3) * 2;
        const int px0 = (t & 7) * 4;
        const int ow = sel * 64 + o0;
        float a[2][4];
        #pragma unroll
        for (int j = 0; j < 2; ++j) {
            float b = qkvb[ow + j];
            a[j][0] = b; a[j][1] = b; a[j][2] = b; a[j][3] = b;
        }
        for (int c = 0; c < CC; c += 4) {
            float4 xv[4];
            #pragma unroll
            for (int i = 0; i < 4; ++i) xv[i] = *(float4*)&xs[c + i][px0];
            #pragma unroll
            for (int j = 0; j < 2; ++j) {
                float4 wv = *(const float4*)(qkvw + (ow + j) * CC + c);
                #pragma unroll
                for (int pp = 0; pp < 4; ++pp) {
                    a[j][pp] += wv.x * (&xv[0].x)[pp] + wv.y * (&xv[1].x)[pp]
                              + wv.z * (&xv[2].x)[pp] + wv.w * (&xv[3].x)[pp];
                }
            }
        }
        #pragma unroll
        for (int j = 0; j < 2; ++j) {
            #pragma unroll
            for (int pp = 0; pp < 4; ++pp) qk[px0 + pp][o0 + j] = a[j][pp];
        }
    }
    __syncthreads();

    if (sel < 2) {
        if (t < 128) {
            const int px = ((t >> 6) << 4) + (t & 15);
            const int part = (t & 63) >> 4;
            float s = 0.f, ss = 0.f;
            #pragma unroll
            for (int i = 0; i < 16; ++i) { float v = qk[px][part * 16 + i]; s += v; ss += v * v; }
            s += __shfl_xor(s, 16); ss += __shfl_xor(ss, 16);
            s += __shfl_xor(s, 32); ss += __shfl_xor(ss, 32);
            if (part == 0) {
                float m = s * (1.f / CC);
                mu2[px] = m;
                rs2[px] = rsqrtf(ss * (1.f / CC) - m * m + EPSV);
            }
        }
        __syncthreads();
    }

    const float* lw = (sel == 0) ? qnw : knw;
    const float* lb = (sel == 0) ? qnb : knb;
    float* dst = (sel == 0) ? qo : ((sel == 1) ? ko : vo);
    #pragma unroll
    for (int pass = 0; pass < 2; ++pass) {
        const int px = (t >> 4) + pass * 16;
        const int cg = t & 15;
        const int c = cg * 4;
        const int hd = cg >> 1;
        const int d4 = (cg & 1) * 4;
        const int pixel = pix0 + px;
        const int h = pixel >> 7, w = pixel & 127;
        const int pos = ((h >> 2) * 32 + (w >> 2)) * 16 + (h & 3) * 4 + (w & 3);
        const int gbase = hd * HDSTR + pos * 8 + d4;

        float4 vv = *(float4*)&qk[px][c];
        if (sel < 2) {
            const float mm = mu2[px], rr = rs2[px];
            float4 w4 = *(const float4*)(lw + c);
            float4 b4 = *(const float4*)(lb + c);
            vv.x = (vv.x - mm) * rr * w4.x + b4.x;
            vv.y = (vv.y - mm) * rr * w4.y + b4.y;
            vv.z = (vv.z - mm) * rr * w4.z + b4.z;
            vv.w = (vv.w - mm) * rr * w4.w + b4.w;
        }
        *(float4*)(dst + gbase) = vv;
    }
}

// ---------------- Kernel B: subgrid NAT + bf16 weight conversion for C ----------------
__global__ __launch_bounds__(256) void k_attn(
    const float* __restrict__ q, const float* __restrict__ k, const float* __restrict__ v,
    float* __restrict__ o,
    const float* __restrict__ pw, const float* __restrict__ f1w, const float* __restrict__ f2w,
    unsigned short* __restrict__ pwh, unsigned short* __restrict__ f1h,
    unsigned short* __restrict__ f2h)
{
    __shared__ __align__(16) float kt[4][15][33][2];
    __shared__ __align__(16) float vt[4][15][33][2];

    const int t = threadIdx.x;
    const int band = blockIdx.x;
    const int sub  = blockIdx.y;
    const int head = blockIdx.z;
    const int hs0 = band * 8;

    // one-shot bf16 conversion of C's weights (20480 elems over 131072 threads)
    {
        const int gtid = ((blockIdx.z * 16 + blockIdx.y) * 4 + blockIdx.x) * 256 + t;
        if (gtid < 4096)        pwh[gtid] = f2bf(pw[gtid]);
        else if (gtid < 12288)  f1h[gtid - 4096] = f2bf(f1w[gtid - 4096]);
        else if (gtid < 20480)  f2h[gtid - 12288] = f2bf(f2w[gtid - 12288]);
    }

    const float* kb = k + head * HDSTR;
    const float* vb = v + head * HDSTR;

    for (int idx = t; idx < 960; idx += 256) {
        const int row = idx >> 6;
        const int rem = idx & 63;
        const int wsc = rem >> 1;
        const int dh = rem & 1;
        int gr = hs0 - 4 + row;
        gr = gr < 0 ? 0 : (gr > 31 ? 31 : gr);
        const int gaddr = ((gr * 32 + wsc) * 16 + sub) * 8 + dh * 4;
        const float4 kv4 = *(const float4*)(kb + gaddr);
        const float4 vv4 = *(const float4*)(vb + gaddr);
        const int dp = dh * 2;
        kt[dp][row][wsc][0] = kv4.x;     kt[dp][row][wsc][1] = kv4.y;
        kt[dp + 1][row][wsc][0] = kv4.z; kt[dp + 1][row][wsc][1] = kv4.w;
        vt[dp][row][wsc][0] = vv4.x;     vt[dp][row][wsc][1] = vv4.y;
        vt[dp + 1][row][wsc][0] = vv4.z; vt[dp + 1][row][wsc][1] = vv4.w;
    }

    const int r = t >> 5;
    const int wsc = t & 31;
    const int hs = hs0 + r;

    const float* qp = q + head * HDSTR + ((hs * 32 + wsc) * 16 + sub) * 8;
    const float4 q0 = *(const float4*)qp;
    const float4 q1 = *(const float4*)(qp + 4);
    const float scale = 0.35355339059327373f;

    __syncthreads();

    float s[64];
    float mx0 = -1e30f, mx1 = -1e30f, mx2 = -1e30f, mx3 = -1e30f;
    #pragma unroll
    for (int i = 0; i < 8; ++i) {
        const int lr = r + i;
        const bool vh = (unsigned)(hs + i - 4) < 32u;
        #pragma unroll
        for (int j = 0; j < 8; ++j) {
            const int cs = wsc + j - 4;
            const bool valid = vh && ((unsigned)cs < 32u);
            const int cc = cs < 0 ? 0 : (cs > 31 ? 31 : cs);
            const float2 kA = *(const float2*)&kt[0][lr][cc][0];
            const float2 kB = *(const float2*)&kt[1][lr][cc][0];
            const float2 kC = *(const float2*)&kt[2][lr][cc][0];
            const float2 kD = *(const float2*)&kt[3][lr][cc][0];
            float sv = q0.x * kA.x + q0.y * kA.y + q0.z * kB.x + q0.w * kB.y
                     + q1.x * kC.x + q1.y * kC.y + q1.z * kD.x + q1.w * kD.y;
            sv *= scale;
            sv = valid ? sv : -INFINITY;
            s[i * 8 + j] = sv;
            if ((j & 3) == 0)      mx0 = fmaxf(mx0, sv);
            else if ((j & 3) == 1) mx1 = fmaxf(mx1, sv);
            else if ((j & 3) == 2) mx2 = fmaxf(mx2, sv);
            else                   mx3 = fmaxf(mx3, sv);
        }
    }
    const float mx = fmaxf(fmaxf(mx0, mx1), fmaxf(mx2, mx3));

    float l = 0.f;
    float a0 = 0.f, a1 = 0.f, a2 = 0.f, a3 = 0.f, a4 = 0.f, a5 = 0.f, a6 = 0.f, a7 = 0.f;
    #pragma unroll
    for (int i = 0; i < 8; ++i) {
        const int lr = r + i;
        #pragma unroll
        for (int j = 0; j < 8; ++j) {
            const int cs = wsc + j - 4;
            const int cc = cs < 0 ? 0 : (cs > 31 ? 31 : cs);
            const float p = __expf(s[i * 8 + j] - mx);
            const float2 vA = *(const float2*)&vt[0][lr][cc][0];
            const float2 vB = *(const float2*)&vt[1][lr][cc][0];
            const float2 vC = *(const float2*)&vt[2][lr][cc][0];
            const float2 vD = *(const float2*)&vt[3][lr][cc][0];
            l += p;
            a0 += p * vA.x;  a1 += p * vA.y;
            a2 += p * vB.x;  a3 += p * vB.y;
            a4 += p * vC.x;  a5 += p * vC.y;
            a6 += p * vD.x;  a7 += p * vD.y;
        }
    }

    const float inv = 1.f / l;
    const int a = sub >> 2, b = sub & 3;
    const int h = hs * 4 + a, w = wsc * 4 + b;
    float* op = o + (h * 128 + w) * 64 + head * 8;
    float4 r0 = {a0 * inv, a1 * inv, a2 * inv, a3 * inv};
    float4 r1 = {a4 * inv, a5 * inv, a6 * inv, a7 * inv};
    *(float4*)op = r0;
    *(float4*)(op + 4) = r1;
}

// ---------------- Kernel C: MFMA proj/fc1/fc2 + VALU LayerNorms ----------------
// GEMMs via mfma_f32_16x16x32_bf16. Activations bf16 px-major [px][chan] in LDS
// (B^T-style feed: lane reads col=lane&15, k=(lane>>4)*8.. — m97-verified pattern).
// C/D frag: col(px)=lane&15, row(out)=(lane>>4)*4+reg (m89-verified).
__global__ __launch_bounds__(256) void k_mlp(
    const float* __restrict__ x, const float* __restrict__ oatt,
    const unsigned short* __restrict__ pwh, const float* __restrict__ pb,
    const float* __restrict__ g1,
    const float* __restrict__ n2w, const float* __restrict__ n2b,
    const unsigned short* __restrict__ f1h, const float* __restrict__ f1b,
    const float* __restrict__ mnw, const float* __restrict__ mnb,
    const unsigned short* __restrict__ f2h, const float* __restrict__ f2b,
    const float* __restrict__ g2,
    float* __restrict__ out)
{
    __shared__ __align__(16) float xres[CC][ROW];
    __shared__ __align__(16) unsigned short oh[32][72];    // oatt bf16 [px][chan]
    __shared__ __align__(16) unsigned short tbh[32][72];   // ln2(x) bf16 [px][chan]
    __shared__ __align__(16) float h1[HID][ROW];           // fc1 out fp32 [chan][px]
    __shared__ __align__(16) unsigned short h1h[32][136];  // silu(mn) bf16 [px][chan]
    __shared__ __align__(16) float mu[32], rs[32];

    const int t = threadIdx.x;
    const int pix0 = blockIdx.x * 32;
    const int wv = t >> 6;      // wave 0..3
    const int l = t & 63;
    const int ln = l & 15;      // frag col (px within 16-half / weight row within stripe)
    const int kg = l >> 4;      // frag k-group

    // load x -> xres fp32; oatt -> oh bf16
    {
        const int c = t >> 2, pxq = (t & 3) * 8;
        *(float4*)&xres[c][pxq]     = *(const float4*)(x + c * HW + pix0 + pxq);
        *(float4*)&xres[c][pxq + 4] = *(const float4*)(x + c * HW + pix0 + pxq + 4);
    }
    #pragma unroll
    for (int pass = 0; pass < 2; ++pass) {
        const int px = (t >> 4) + pass * 16, cg = (t & 15) * 4;
        float4 ov = *(const float4*)(oatt + (pix0 + px) * CC + cg);
        *(unsigned*)&oh[px][cg]     = pack2bf(ov.x, ov.y);
        *(unsigned*)&oh[px][cg + 2] = pack2bf(ov.z, ov.w);
    }
    __syncthreads();

    // ---- proj (64x64 @ K=64) via MFMA; xres += g1*(D + pb) ----
    {
        f32x4v acc0 = {0.f, 0.f, 0.f, 0.f}, acc1 = {0.f, 0.f, 0.f, 0.f};
        const int m = wv * 16 + ln;
        #pragma unroll
        for (int kk = 0; kk < 64; kk += 32) {
            const int k0 = kk + kg * 8;
            bf16x8 av = *(const bf16x8*)(pwh + m * 64 + k0);
            bf16x8 b0 = *(const bf16x8*)&oh[ln][k0];
            bf16x8 b1 = *(const bf16x8*)&oh[16 + ln][k0];
            acc0 = __builtin_amdgcn_mfma_f32_16x16x32_bf16(av, b0, acc0, 0, 0, 0);
            acc1 = __builtin_amdgcn_mfma_f32_16x16x32_bf16(av, b1, acc1, 0, 0, 0);
        }
        const int r0 = wv * 16 + kg * 4;
        float4 pb4 = *(const float4*)(pb + r0);
        float4 g14 = *(const float4*)(g1 + r0);
        #pragma unroll
        for (int reg = 0; reg < 4; ++reg) {
            const int row = r0 + reg;
            xres[row][ln]      += (&g14.x)[reg] * (acc0[reg] + (&pb4.x)[reg]);
            xres[row][16 + ln] += (&g14.x)[reg] * (acc1[reg] + (&pb4.x)[reg]);
        }
    }
    __syncthreads();

    // ln2 stats
    if (t < 128) {
        const int px = ((t >> 6) << 4) + (t & 15);
        const int part = (t & 63) >> 4;
        float s = 0.f, ss = 0.f;
        #pragma unroll
        for (int i = 0; i < 16; ++i) { float v = xres[part * 16 + i][px]; s += v; ss += v * v; }
        s += __shfl_xor(s, 16); ss += __shfl_xor(ss, 16);
        s += __shfl_xor(s, 32); ss += __shfl_xor(ss, 32);
        if (part == 0) {
            float m = s * (1.f / CC);
            mu[px] = m;
            rs[px] = rsqrtf(ss * (1.f / CC) - m * m + EPSV);
        }
    }
    __syncthreads();

    // apply ln2 -> tbh bf16 (2 chans x 4 px per thread, packed u32 writes)
    {
        const int c2 = (t & 31) * 2, px0 = (t >> 5) * 4;
        const float w0 = n2w[c2], b0 = n2b[c2];
        const float w1 = n2w[c2 + 1], b1 = n2b[c2 + 1];
        float4 va = *(float4*)&xres[c2][px0];
        float4 vb = *(float4*)&xres[c2 + 1][px0];
        float4 m4 = *(float4*)&mu[px0];
        float4 r4 = *(float4*)&rs[px0];
        #pragma unroll
        for (int i = 0; i < 4; ++i) {
            float f0 = ((&va.x)[i] - (&m4.x)[i]) * (&r4.x)[i] * w0 + b0;
            float f1 = ((&vb.x)[i] - (&m4.x)[i]) * (&r4.x)[i] * w1 + b1;
            *(unsigned*)&tbh[px0 + i][c2] = pack2bf(f0, f1);
        }
    }
    __syncthreads();

    // ---- fc1 (128x64 @ K=64) via MFMA -> h1 fp32 ----
    {
        f32x4v a00 = {0.f,0.f,0.f,0.f}, a01 = {0.f,0.f,0.f,0.f};
        f32x4v a10 = {0.f,0.f,0.f,0.f}, a11 = {0.f,0.f,0.f,0.f};
        const int m0 = wv * 32 + ln;
        #pragma unroll
        for (int kk = 0; kk < 64; kk += 32) {
            const int k0 = kk + kg * 8;
            bf16x8 av0 = *(const bf16x8*)(f1h + m0 * 64 + k0);
            bf16x8 av1 = *(const bf16x8*)(f1h + (m0 + 16) * 64 + k0);
            bf16x8 b0 = *(const bf16x8*)&tbh[ln][k0];
            bf16x8 b1 = *(const bf16x8*)&tbh[16 + ln][k0];
            a00 = __builtin_amdgcn_mfma_f32_16x16x32_bf16(av0, b0, a00, 0, 0, 0);
            a01 = __builtin_amdgcn_mfma_f32_16x16x32_bf16(av0, b1, a01, 0, 0, 0);
            a10 = __builtin_amdgcn_mfma_f32_16x16x32_bf16(av1, b0, a10, 0, 0, 0);
            a11 = __builtin_amdgcn_mfma_f32_16x16x32_bf16(av1, b1, a11, 0, 0, 0);
        }
        const int r0 = wv * 32 + kg * 4;
        float4 fb0 = *(const float4*)(f1b + r0);
        float4 fb1 = *(const float4*)(f1b + r0 + 16);
        #pragma unroll
        for (int reg = 0; reg < 4; ++reg) {
            h1[r0 + reg][ln]           = a00[reg] + (&fb0.x)[reg];
            h1[r0 + reg][16 + ln]      = a01[reg] + (&fb0.x)[reg];
            h1[r0 + 16 + reg][ln]      = a10[reg] + (&fb1.x)[reg];
            h1[r0 + 16 + reg][16 + ln] = a11[reg] + (&fb1.x)[reg];
        }
    }
    __syncthreads();

    // mn stats over 128 channels
    if (t < 128) {
        const int px = ((t >> 6) << 4) + (t & 15);
        const int part = (t & 63) >> 4;
        float s = 0.f, ss = 0.f;
        #pragma unroll
        for (int i = 0; i < 32; ++i) { float v = h1[part * 32 + i][px]; s += v; ss += v * v; }
        s += __shfl_xor(s, 16); ss += __shfl_xor(ss, 16);
        s += __shfl_xor(s, 32); ss += __shfl_xor(ss, 32);
        if (part == 0) {
            float m = s * (1.f / HID);
            mu[px] = m;
            rs[px] = rsqrtf(ss * (1.f / HID) - m * m + EPSV);
        }
    }
    __syncthreads();

    // apply mn LN + silu -> h1h bf16 (2 chans x 8 px per thread)
    {
        const int c2 = (t & 63) * 2, pxm = (t >> 6) * 8;
        const float w0 = mnw[c2], b0 = mnb[c2];
        const float w1 = mnw[c2 + 1], b1 = mnb[c2 + 1];
        #pragma unroll
        for (int qq = 0; qq < 2; ++qq) {
            float4 va = *(float4*)&h1[c2][pxm + qq * 4];
            float4 vb = *(float4*)&h1[c2 + 1][pxm + qq * 4];
            float4 m4 = *(float4*)&mu[pxm + qq * 4];
            float4 r4 = *(float4*)&rs[pxm + qq * 4];
            #pragma unroll
            for (int i = 0; i < 4; ++i) {
                float h0 = ((&va.x)[i] - (&m4.x)[i]) * (&r4.x)[i] * w0 + b0;
                float h1v = ((&vb.x)[i] - (&m4.x)[i]) * (&r4.x)[i] * w1 + b1;
                h0 = h0 / (1.f + __expf(-h0));
                h1v = h1v / (1.f + __expf(-h1v));
                *(unsigned*)&h1h[pxm + qq * 4 + i][c2] = pack2bf(h0, h1v);
            }
        }
    }
    __syncthreads();

    // ---- fc2 (64x128 @ K=128) via MFMA; out = xres + g2*(D + f2b) ----
    {
        f32x4v acc0 = {0.f, 0.f, 0.f, 0.f}, acc1 = {0.f, 0.f, 0.f, 0.f};
        const int m = wv * 16 + ln;
        #pragma unroll
        for (int kk = 0; kk < 128; kk += 32) {
            const int k0 = kk + kg * 8;
            bf16x8 av = *(const bf16x8*)(f2h + m * 128 + k0);
            bf16x8 b0 = *(const bf16x8*)&h1h[ln][k0];
            bf16x8 b1 = *(const bf16x8*)&h1h[16 + ln][k0];
            acc0 = __builtin_amdgcn_mfma_f32_16x16x32_bf16(av, b0, acc0, 0, 0, 0);
            acc1 = __builtin_amdgcn_mfma_f32_16x16x32_bf16(av, b1, acc1, 0, 0, 0);
        }
        const int r0 = wv * 16 + kg * 4;
        float4 fb4 = *(const float4*)(f2b + r0);
        float4 g24 = *(const float4*)(g2 + r0);
        #pragma unroll
        for (int reg = 0; reg < 4; ++reg) {
            const int row = r0 + reg;
            out[row * HW + pix0 + ln]      = xres[row][ln]
                                           + (&g24.x)[reg] * (acc0[reg] + (&fb4.x)[reg]);
            out[row * HW + pix0 + 16 + ln] = xres[row][16 + ln]
                                           + (&g24.x)[reg] * (acc1[reg] + (&fb4.x)[reg]);
        }
    }
}

extern "C" void kernel_launch(void* const* d_in, const int* in_sizes, int n_in,
                              void* d_out, int out_size, void* d_ws, size_t ws_size,
                              hipStream_t stream) {
    (void)in_sizes; (void)n_in; (void)out_size; (void)ws_size;
    const float* x      = (const float*)d_in[0];
    const float* n1w    = (const float*)d_in[1];
    const float* n1b    = (const float*)d_in[2];
    const float* qkvw   = (const float*)d_in[3];
    const float* qkvb   = (const float*)d_in[4];
    const float* qnw    = (const float*)d_in[5];
    const float* qnb    = (const float*)d_in[6];
    const float* knw    = (const float*)d_in[7];
    const float* knb    = (const float*)d_in[8];
    const float* pw     = (const float*)d_in[9];
    const float* pb     = (const float*)d_in[10];
    const float* g1     = (const float*)d_in[11];
    const float* n2w    = (const float*)d_in[12];
    const float* n2b    = (const float*)d_in[13];
    const float* f1w    = (const float*)d_in[14];
    const float* f1b    = (const float*)d_in[15];
    const float* mnw    = (const float*)d_in[16];
    const float* mnb    = (const float*)d_in[17];
    const float* f2w    = (const float*)d_in[18];
    const float* f2b    = (const float*)d_in[19];
    const float* g2     = (const float*)d_in[20];
    float* out = (float*)d_out;

    float* ws = (float*)d_ws;
    const size_t CHW = (size_t)CC * HW;   // 1,048,576 floats
    float* qo   = ws;
    float* ko   = ws + CHW;
    float* vo   = ws + 2 * CHW;
    float* oatt = ws + 3 * CHW;
    unsigned short* wsh = (unsigned short*)(ws + 4 * CHW);
    unsigned short* pwh = wsh;            // 4096
    unsigned short* f1h = wsh + 4096;     // 8192
    unsigned short* f2h = wsh + 12288;    // 8192

    k_ln_qkv<<<dim3(HW / 32, 3), dim3(256), 0, stream>>>(
        x, n1w, n1b, qkvw, qkvb, qnw, qnb, knw, knb, qo, ko, vo);
    k_attn<<<dim3(4, 16, 8), dim3(256), 0, stream>>>(
        qo, ko, vo, oatt, pw, f1w, f2w, pwh, f1h, f2h);
    k_mlp<<<dim3(HW / 32), dim3(256), 0, stream>>>(
        x, oatt, pwh, pb, g1, n2w, n2b, f1h, f1b, mnw, mnb, f2h, f2b, g2, out);
}

// Round 8
// 131.644 us; speedup vs baseline: 1.9350x; 1.0316x over previous
//
#include <hip/hip_runtime.h>
#include <math.h>

#define HW 16384
#define CC 64
#define HID 128
#define EPSV 1e-5f
#define ROW 36     // padded LDS row for 32-pixel fp32 tiles
#define QROW 197   // padded per-pixel row for qkv fp32 staging (192 + 5, odd)
#define HDSTR 131072    // per-head stride: 32*32*16*8 floats

typedef __attribute__((ext_vector_type(8))) short bf16x8;   // 8 bf16 = 4 VGPRs
typedef __attribute__((ext_vector_type(4))) float f32x4v;   // MFMA accumulator

__device__ __forceinline__ unsigned short f2bf(float f) {   // RNE fp32->bf16
    unsigned u = __float_as_uint(f);
    u += 0x7FFFu + ((u >> 16) & 1u);
    return (unsigned short)(u >> 16);
}
__device__ __forceinline__ unsigned pack2bf(float a, float b) {
    return (unsigned)f2bf(a) | ((unsigned)f2bf(b) << 16);
}

// q/k/v layout: [head][(hs*32+ws)*16 + sub][8], sub = (h&3)*4 + (w&3)

// ---------------- Kernel A: ln1 -> qkv via MFMA -> q/k LN -> ws ----------------
// One block per 32-px tile. qkv weights converted fp32->bf16 into LDS per block
// (L2-resident). GEMM M=192,N=32,K=64 via mfma_f32_16x16x32_bf16 using the
// r7-harness-verified fragment pattern (A: lane=row in 16-stripe, 8k at kg*8;
// B: px-major [px][chan]; C/D: col=lane&15, row=(lane>>4)*4+reg).
__global__ __launch_bounds__(256) void k_ln_qkv(
    const float* __restrict__ x,
    const float* __restrict__ n1w, const float* __restrict__ n1b,
    const float* __restrict__ qkvw, const float* __restrict__ qkvb,
    const float* __restrict__ qnw, const float* __restrict__ qnb,
    const float* __restrict__ knw, const float* __restrict__ knb,
    float* __restrict__ qo, float* __restrict__ ko, float* __restrict__ vo)
{
    __shared__ __align__(16) float xs[CC][ROW];              // fp32 x tile [chan][px]
    __shared__ __align__(16) unsigned short xh[32][72];      // ln1(x) bf16 [px][chan]
    __shared__ __align__(16) unsigned short wh[192][72];     // qkvw bf16 [out][k] (144B rows, 16-aligned)
    __shared__ __align__(16) float qk[32][QROW];             // qkv out fp32 [px][out]
    __shared__ __align__(16) float mu1[32], rs1[32], muq[32], rsq[32], muk[32], rsk[32];

    const int t = threadIdx.x;
    const int pix0 = blockIdx.x * 32;
    const int wv = t >> 6;      // wave 0..3
    const int l = t & 63;
    const int ln = l & 15;      // frag col (px) / A-row within 16-stripe
    const int kg = l >> 4;      // frag k-group

    // load x tile [c][px], 2 float4 per thread
    {
        const int c = t >> 2, pxq = (t & 3) * 8;
        *(float4*)&xs[c][pxq]     = *(const float4*)(x + c * HW + pix0 + pxq);
        *(float4*)&xs[c][pxq + 4] = *(const float4*)(x + c * HW + pix0 + pxq + 4);
    }
    // load + convert qkv weights (12288 f32 = 3072 float4; 12 per thread)
    #pragma unroll
    for (int i = 0; i < 12; ++i) {
        const int f = i * 256 + t;        // float4 index 0..3071
        const int row = f >> 4;           // weight out-row 0..191
        const int k4 = (f & 15) * 4;      // k offset 0..60
        float4 wv4 = *(const float4*)(qkvw + row * 64 + k4);
        *(unsigned*)&wh[row][k4]     = pack2bf(wv4.x, wv4.y);
        *(unsigned*)&wh[row][k4 + 2] = pack2bf(wv4.z, wv4.w);
    }
    __syncthreads();

    // ln1 stats: waves 0,1 each cover 16 px (4 partials x 16 px)
    if (t < 128) {
        const int px = ((t >> 6) << 4) + (t & 15);
        const int part = (t & 63) >> 4;
        float s = 0.f, ss = 0.f;
        #pragma unroll
        for (int i = 0; i < 16; ++i) { float v = xs[part * 16 + i][px]; s += v; ss += v * v; }
        s += __shfl_xor(s, 16); ss += __shfl_xor(ss, 16);
        s += __shfl_xor(s, 32); ss += __shfl_xor(ss, 32);
        if (part == 0) {
            float m = s * (1.f / CC);
            mu1[px] = m;
            rs1[px] = rsqrtf(ss * (1.f / CC) - m * m + EPSV);
        }
    }
    __syncthreads();

    // apply ln1 -> xh bf16 [px][chan] (2 chans x 4 px per thread, packed u32)
    {
        const int c2 = (t & 31) * 2, px0 = (t >> 5) * 4;
        const float w0 = n1w[c2], b0 = n1b[c2];
        const float w1 = n1w[c2 + 1], b1 = n1b[c2 + 1];
        float4 va = *(float4*)&xs[c2][px0];
        float4 vb = *(float4*)&xs[c2 + 1][px0];
        float4 m4 = *(float4*)&mu1[px0];
        float4 r4 = *(float4*)&rs1[px0];
        #pragma unroll
        for (int i = 0; i < 4; ++i) {
            float f0 = ((&va.x)[i] - (&m4.x)[i]) * (&r4.x)[i] * w0 + b0;
            float f1 = ((&vb.x)[i] - (&m4.x)[i]) * (&r4.x)[i] * w1 + b1;
            *(unsigned*)&xh[px0 + i][c2] = pack2bf(f0, f1);
        }
    }
    __syncthreads();

    // qkv GEMM via MFMA: M=192 (48 rows/wave = 3 m-tiles), N=32 (2 col-tiles), K=64
    {
        f32x4v acc[3][2];
        #pragma unroll
        for (int mt = 0; mt < 3; ++mt) {
            acc[mt][0] = (f32x4v){0.f, 0.f, 0.f, 0.f};
            acc[mt][1] = (f32x4v){0.f, 0.f, 0.f, 0.f};
        }
        const int mbase = wv * 48;
        #pragma unroll
        for (int kk = 0; kk < 64; kk += 32) {
            const int k0 = kk + kg * 8;
            bf16x8 b0 = *(const bf16x8*)&xh[ln][k0];
            bf16x8 b1 = *(const bf16x8*)&xh[16 + ln][k0];
            #pragma unroll
            for (int mt = 0; mt < 3; ++mt) {
                bf16x8 av = *(const bf16x8*)&wh[mbase + mt * 16 + ln][k0];
                acc[mt][0] = __builtin_amdgcn_mfma_f32_16x16x32_bf16(av, b0, acc[mt][0], 0, 0, 0);
                acc[mt][1] = __builtin_amdgcn_mfma_f32_16x16x32_bf16(av, b1, acc[mt][1], 0, 0, 0);
            }
        }
        #pragma unroll
        for (int mt = 0; mt < 3; ++mt) {
            const int r0 = mbase + mt * 16 + kg * 4;
            float4 qb4 = *(const float4*)(qkvb + r0);
            #pragma unroll
            for (int reg = 0; reg < 4; ++reg) {
                qk[ln][r0 + reg]      = acc[mt][0][reg] + (&qb4.x)[reg];
                qk[16 + ln][r0 + reg] = acc[mt][1][reg] + (&qb4.x)[reg];
            }
        }
    }
    __syncthreads();

    // q stats (waves 0,1) and k stats (waves 2,3)
    if (t < 128) {
        const int px = ((t >> 6) << 4) + (t & 15);
        const int part = (t & 63) >> 4;
        float s = 0.f, ss = 0.f;
        #pragma unroll
        for (int i = 0; i < 16; ++i) { float v = qk[px][part * 16 + i]; s += v; ss += v * v; }
        s += __shfl_xor(s, 16); ss += __shfl_xor(ss, 16);
        s += __shfl_xor(s, 32); ss += __shfl_xor(ss, 32);
        if (part == 0) {
            float m = s * (1.f / CC);
            muq[px] = m;
            rsq[px] = rsqrtf(ss * (1.f / CC) - m * m + EPSV);
        }
    } else {
        const int t2 = t - 128;
        const int px = ((t2 >> 6) << 4) + (t2 & 15);
        const int part = (t2 & 63) >> 4;
        float s = 0.f, ss = 0.f;
        #pragma unroll
        for (int i = 0; i < 16; ++i) { float v = qk[px][CC + part * 16 + i]; s += v; ss += v * v; }
        s += __shfl_xor(s, 16); ss += __shfl_xor(ss, 16);
        s += __shfl_xor(s, 32); ss += __shfl_xor(ss, 32);
        if (part == 0) {
            float m = s * (1.f / CC);
            muk[px] = m;
            rsk[px] = rsqrtf(ss * (1.f / CC) - m * m + EPSV);
        }
    }
    __syncthreads();

    // write q (LN), k (LN), v to interleaved subgrid layout
    #pragma unroll
    for (int pass = 0; pass < 2; ++pass) {
        const int px = (t >> 4) + pass * 16;
        const int cg = t & 15;
        const int c = cg * 4;
        const int hd = cg >> 1;
        const int d4 = (cg & 1) * 4;
        const int pixel = pix0 + px;
        const int h = pixel >> 7, w = pixel & 127;
        const int pos = ((h >> 2) * 32 + (w >> 2)) * 16 + (h & 3) * 4 + (w & 3);
        const int gbase = hd * HDSTR + pos * 8 + d4;

        const float mq = muq[px], rq = rsq[px];
        float4 qv = *(float4*)&qk[px][c];
        float4 qw = *(const float4*)(qnw + c);
        float4 qb = *(const float4*)(qnb + c);
        qv.x = (qv.x - mq) * rq * qw.x + qb.x;
        qv.y = (qv.y - mq) * rq * qw.y + qb.y;
        qv.z = (qv.z - mq) * rq * qw.z + qb.z;
        qv.w = (qv.w - mq) * rq * qw.w + qb.w;
        *(float4*)(qo + gbase) = qv;

        const float mk = muk[px], rk = rsk[px];
        float4 kv = *(float4*)&qk[px][CC + c];
        float4 kw = *(const float4*)(knw + c);
        float4 kb = *(const float4*)(knb + c);
        kv.x = (kv.x - mk) * rk * kw.x + kb.x;
        kv.y = (kv.y - mk) * rk * kw.y + kb.y;
        kv.z = (kv.z - mk) * rk * kw.z + kb.z;
        kv.w = (kv.w - mk) * rk * kw.w + kb.w;
        *(float4*)(ko + gbase) = kv;

        float4 vv = *(float4*)&qk[px][2 * CC + c];
        *(float4*)(vo + gbase) = vv;
    }
}

// ---------------- Kernel B: subgrid NAT + bf16 weight conversion for C ----------------
__global__ __launch_bounds__(256) void k_attn(
    const float* __restrict__ q, const float* __restrict__ k, const float* __restrict__ v,
    float* __restrict__ o,
    const float* __restrict__ pw, const float* __restrict__ f1w, const float* __restrict__ f2w,
    unsigned short* __restrict__ pwh, unsigned short* __restrict__ f1h,
    unsigned short* __restrict__ f2h)
{
    __shared__ __align__(16) float kt[4][15][33][2];
    __shared__ __align__(16) float vt[4][15][33][2];

    const int t = threadIdx.x;
    const int band = blockIdx.x;
    const int sub  = blockIdx.y;
    const int head = blockIdx.z;
    const int hs0 = band * 8;

    // one-shot bf16 conversion of C's weights (20480 elems over 131072 threads)
    {
        const int gtid = ((blockIdx.z * 16 + blockIdx.y) * 4 + blockIdx.x) * 256 + t;
        if (gtid < 4096)        pwh[gtid] = f2bf(pw[gtid]);
        else if (gtid < 12288)  f1h[gtid - 4096] = f2bf(f1w[gtid - 4096]);
        else if (gtid < 20480)  f2h[gtid - 12288] = f2bf(f2w[gtid - 12288]);
    }

    const float* kb = k + head * HDSTR;
    const float* vb = v + head * HDSTR;

    for (int idx = t; idx < 960; idx += 256) {
        const int row = idx >> 6;
        const int rem = idx & 63;
        const int wsc = rem >> 1;
        const int dh = rem & 1;
        int gr = hs0 - 4 + row;
        gr = gr < 0 ? 0 : (gr > 31 ? 31 : gr);
        const int gaddr = ((gr * 32 + wsc) * 16 + sub) * 8 + dh * 4;
        const float4 kv4 = *(const float4*)(kb + gaddr);
        const float4 vv4 = *(const float4*)(vb + gaddr);
        const int dp = dh * 2;
        kt[dp][row][wsc][0] = kv4.x;     kt[dp][row][wsc][1] = kv4.y;
        kt[dp + 1][row][wsc][0] = kv4.z; kt[dp + 1][row][wsc][1] = kv4.w;
        vt[dp][row][wsc][0] = vv4.x;     vt[dp][row][wsc][1] = vv4.y;
        vt[dp + 1][row][wsc][0] = vv4.z; vt[dp + 1][row][wsc][1] = vv4.w;
    }

    const int r = t >> 5;
    const int wsc = t & 31;
    const int hs = hs0 + r;

    const float* qp = q + head * HDSTR + ((hs * 32 + wsc) * 16 + sub) * 8;
    const float4 q0 = *(const float4*)qp;
    const float4 q1 = *(const float4*)(qp + 4);
    const float scale = 0.35355339059327373f;

    __syncthreads();

    float s[64];
    float mx0 = -1e30f, mx1 = -1e30f, mx2 = -1e30f, mx3 = -1e30f;
    #pragma unroll
    for (int i = 0; i < 8; ++i) {
        const int lr = r + i;
        const bool vh = (unsigned)(hs + i - 4) < 32u;
        #pragma unroll
        for (int j = 0; j < 8; ++j) {
            const int cs = wsc + j - 4;
            const bool valid = vh && ((unsigned)cs < 32u);
            const int cc = cs < 0 ? 0 : (cs > 31 ? 31 : cs);
            const float2 kA = *(const float2*)&kt[0][lr][cc][0];
            const float2 kB = *(const float2*)&kt[1][lr][cc][0];
            const float2 kC = *(const float2*)&kt[2][lr][cc][0];
            const float2 kD = *(const float2*)&kt[3][lr][cc][0];
            float sv = q0.x * kA.x + q0.y * kA.y + q0.z * kB.x + q0.w * kB.y
                     + q1.x * kC.x + q1.y * kC.y + q1.z * kD.x + q1.w * kD.y;
            sv *= scale;
            sv = valid ? sv : -INFINITY;
            s[i * 8 + j] = sv;
            if ((j & 3) == 0)      mx0 = fmaxf(mx0, sv);
            else if ((j & 3) == 1) mx1 = fmaxf(mx1, sv);
            else if ((j & 3) == 2) mx2 = fmaxf(mx2, sv);
            else                   mx3 = fmaxf(mx3, sv);
        }
    }
    const float mx = fmaxf(fmaxf(mx0, mx1), fmaxf(mx2, mx3));

    float l = 0.f;
    float a0 = 0.f, a1 = 0.f, a2 = 0.f, a3 = 0.f, a4 = 0.f, a5 = 0.f, a6 = 0.f, a7 = 0.f;
    #pragma unroll
    for (int i = 0; i < 8; ++i) {
        const int lr = r + i;
        #pragma unroll
        for (int j = 0; j < 8; ++j) {
            const int cs = wsc + j - 4;
            const int cc = cs < 0 ? 0 : (cs > 31 ? 31 : cs);
            const float p = __expf(s[i * 8 + j] - mx);
            const float2 vA = *(const float2*)&vt[0][lr][cc][0];
            const float2 vB = *(const float2*)&vt[1][lr][cc][0];
            const float2 vC = *(const float2*)&vt[2][lr][cc][0];
            const float2 vD = *(const float2*)&vt[3][lr][cc][0];
            l += p;
            a0 += p * vA.x;  a1 += p * vA.y;
            a2 += p * vB.x;  a3 += p * vB.y;
            a4 += p * vC.x;  a5 += p * vC.y;
            a6 += p * vD.x;  a7 += p * vD.y;
        }
    }

    const float inv = 1.f / l;
    const int a = sub >> 2, b = sub & 3;
    const int h = hs * 4 + a, w = wsc * 4 + b;
    float* op = o + (h * 128 + w) * 64 + head * 8;
    float4 r0 = {a0 * inv, a1 * inv, a2 * inv, a3 * inv};
    float4 r1 = {a4 * inv, a5 * inv, a6 * inv, a7 * inv};
    *(float4*)op = r0;
    *(float4*)(op + 4) = r1;
}

// ---------------- Kernel C: MFMA proj/fc1/fc2 + VALU LayerNorms (r7-verified) ----------------
__global__ __launch_bounds__(256) void k_mlp(
    const float* __restrict__ x, const float* __restrict__ oatt,
    const unsigned short* __restrict__ pwh, const float* __restrict__ pb,
    const float* __restrict__ g1,
    const float* __restrict__ n2w, const float* __restrict__ n2b,
    const unsigned short* __restrict__ f1h, const float* __restrict__ f1b,
    const float* __restrict__ mnw, const float* __restrict__ mnb,
    const unsigned short* __restrict__ f2h, const float* __restrict__ f2b,
    const float* __restrict__ g2,
    float* __restrict__ out)
{
    __shared__ __align__(16) float xres[CC][ROW];
    __shared__ __align__(16) unsigned short oh[32][72];
    __shared__ __align__(16) unsigned short tbh[32][72];
    __shared__ __align__(16) float h1[HID][ROW];
    __shared__ __align__(16) unsigned short h1h[32][136];
    __shared__ __align__(16) float mu[32], rs[32];

    const int t = threadIdx.x;
    const int pix0 = blockIdx.x * 32;
    const int wv = t >> 6;
    const int l = t & 63;
    const int ln = l & 15;
    const int kg = l >> 4;

    {
        const int c = t >> 2, pxq = (t & 3) * 8;
        *(float4*)&xres[c][pxq]     = *(const float4*)(x + c * HW + pix0 + pxq);
        *(float4*)&xres[c][pxq + 4] = *(const float4*)(x + c * HW + pix0 + pxq + 4);
    }
    #pragma unroll
    for (int pass = 0; pass < 2; ++pass) {
        const int px = (t >> 4) + pass * 16, cg = (t & 15) * 4;
        float4 ov = *(const float4*)(oatt + (pix0 + px) * CC + cg);
        *(unsigned*)&oh[px][cg]     = pack2bf(ov.x, ov.y);
        *(unsigned*)&oh[px][cg + 2] = pack2bf(ov.z, ov.w);
    }
    __syncthreads();

    // proj (64x64 @ K=64); xres += g1*(D + pb)
    {
        f32x4v acc0 = {0.f, 0.f, 0.f, 0.f}, acc1 = {0.f, 0.f, 0.f, 0.f};
        const int m = wv * 16 + ln;
        #pragma unroll
        for (int kk = 0; kk < 64; kk += 32) {
            const int k0 = kk + kg * 8;
            bf16x8 av = *(const bf16x8*)(pwh + m * 64 + k0);
            bf16x8 b0 = *(const bf16x8*)&oh[ln][k0];
            bf16x8 b1 = *(const bf16x8*)&oh[16 + ln][k0];
            acc0 = __builtin_amdgcn_mfma_f32_16x16x32_bf16(av, b0, acc0, 0, 0, 0);
            acc1 = __builtin_amdgcn_mfma_f32_16x16x32_bf16(av, b1, acc1, 0, 0, 0);
        }
        const int r0 = wv * 16 + kg * 4;
        float4 pb4 = *(const float4*)(pb + r0);
        float4 g14 = *(const float4*)(g1 + r0);
        #pragma unroll
        for (int reg = 0; reg < 4; ++reg) {
            const int row = r0 + reg;
            xres[row][ln]      += (&g14.x)[reg] * (acc0[reg] + (&pb4.x)[reg]);
            xres[row][16 + ln] += (&g14.x)[reg] * (acc1[reg] + (&pb4.x)[reg]);
        }
    }
    __syncthreads();

    if (t < 128) {
        const int px = ((t >> 6) << 4) + (t & 15);
        const int part = (t & 63) >> 4;
        float s = 0.f, ss = 0.f;
        #pragma unroll
        for (int i = 0; i < 16; ++i) { float v = xres[part * 16 + i][px]; s += v; ss += v * v; }
        s += __shfl_xor(s, 16); ss += __shfl_xor(ss, 16);
        s += __shfl_xor(s, 32); ss += __shfl_xor(ss, 32);
        if (part == 0) {
            float m = s * (1.f / CC);
            mu[px] = m;
            rs[px] = rsqrtf(ss * (1.f / CC) - m * m + EPSV);
        }
    }
    __syncthreads();

    {
        const int c2 = (t & 31) * 2, px0 = (t >> 5) * 4;
        const float w0 = n2w[c2], b0 = n2b[c2];
        const float w1 = n2w[c2 + 1], b1 = n2b[c2 + 1];
        float4 va = *(float4*)&xres[c2][px0];
        float4 vb = *(float4*)&xres[c2 + 1][px0];
        float4 m4 = *(float4*)&mu[px0];
        float4 r4 = *(float4*)&rs[px0];
        #pragma unroll
        for (int i = 0; i < 4; ++i) {
            float f0 = ((&va.x)[i] - (&m4.x)[i]) * (&r4.x)[i] * w0 + b0;
            float f1 = ((&vb.x)[i] - (&m4.x)[i]) * (&r4.x)[i] * w1 + b1;
            *(unsigned*)&tbh[px0 + i][c2] = pack2bf(f0, f1);
        }
    }
    __syncthreads();

    // fc1 (128x64 @ K=64) -> h1 fp32
    {
        f32x4v a00 = {0.f,0.f,0.f,0.f}, a01 = {0.f,0.f,0.f,0.f};
        f32x4v a10 = {0.f,0.f,0.f,0.f}, a11 = {0.f,0.f,0.f,0.f};
        const int m0 = wv * 32 + ln;
        #pragma unroll
        for (int kk = 0; kk < 64; kk += 32) {
            const int k0 = kk + kg * 8;
            bf16x8 av0 = *(const bf16x8*)(f1h + m0 * 64 + k0);
            bf16x8 av1 = *(const bf16x8*)(f1h + (m0 + 16) * 64 + k0);
            bf16x8 b0 = *(const bf16x8*)&tbh[ln][k0];
            bf16x8 b1 = *(const bf16x8*)&tbh[16 + ln][k0];
            a00 = __builtin_amdgcn_mfma_f32_16x16x32_bf16(av0, b0, a00, 0, 0, 0);
            a01 = __builtin_amdgcn_mfma_f32_16x16x32_bf16(av0, b1, a01, 0, 0, 0);
            a10 = __builtin_amdgcn_mfma_f32_16x16x32_bf16(av1, b0, a10, 0, 0, 0);
            a11 = __builtin_amdgcn_mfma_f32_16x16x32_bf16(av1, b1, a11, 0, 0, 0);
        }
        const int r0 = wv * 32 + kg * 4;
        float4 fb0 = *(const float4*)(f1b + r0);
        float4 fb1 = *(const float4*)(f1b + r0 + 16);
        #pragma unroll
        for (int reg = 0; reg < 4; ++reg) {
            h1[r0 + reg][ln]           = a00[reg] + (&fb0.x)[reg];
            h1[r0 + reg][16 + ln]      = a01[reg] + (&fb0.x)[reg];
            h1[r0 + 16 + reg][ln]      = a10[reg] + (&fb1.x)[reg];
            h1[r0 + 16 + reg][16 + ln] = a11[reg] + (&fb1.x)[reg];
        }
    }
    __syncthreads();

    if (t < 128) {
        const int px = ((t >> 6) << 4) + (t & 15);
        const int part = (t & 63) >> 4;
        float s = 0.f, ss = 0.f;
        #pragma unroll
        for (int i = 0; i < 32; ++i) { float v = h1[part * 32 + i][px]; s += v; ss += v * v; }
        s += __shfl_xor(s, 16); ss += __shfl_xor(ss, 16);
        s += __shfl_xor(s, 32); ss += __shfl_xor(ss, 32);
        if (part == 0) {
            float m = s * (1.f / HID);
            mu[px] = m;
            rs[px] = rsqrtf(ss * (1.f / HID) - m * m + EPSV);
        }
    }
    __syncthreads();

    {
        const int c2 = (t & 63) * 2, pxm = (t >> 6) * 8;
        const float w0 = mnw[c2], b0 = mnb[c2];
        const float w1 = mnw[c2 + 1], b1 = mnb[c2 + 1];
        #pragma unroll
        for (int qq = 0; qq < 2; ++qq) {
            float4 va = *(float4*)&h1[c2][pxm + qq * 4];
            float4 vb = *(float4*)&h1[c2 + 1][pxm + qq * 4];
            float4 m4 = *(float4*)&mu[pxm + qq * 4];
            float4 r4 = *(float4*)&rs[pxm + qq * 4];
            #pragma unroll
            for (int i = 0; i < 4; ++i) {
                float h0 = ((&va.x)[i] - (&m4.x)[i]) * (&r4.x)[i] * w0 + b0;
                float h1v = ((&vb.x)[i] - (&m4.x)[i]) * (&r4.x)[i] * w1 + b1;
                h0 = h0 / (1.f + __expf(-h0));
                h1v = h1v / (1.f + __expf(-h1v));
                *(unsigned*)&h1h[pxm + qq * 4 + i][c2] = pack2bf(h0, h1v);
            }
        }
    }
    __syncthreads();

    // fc2 (64x128 @ K=128); out = xres + g2*(D + f2b)
    {
        f32x4v acc0 = {0.f, 0.f, 0.f, 0.f}, acc1 = {0.f, 0.f, 0.f, 0.f};
        const int m = wv * 16 + ln;
        #pragma unroll
        for (int kk = 0; kk < 128; kk += 32) {
            const int k0 = kk + kg * 8;
            bf16x8 av = *(const bf16x8*)(f2h + m * 128 + k0);
            bf16x8 b0 = *(const bf16x8*)&h1h[ln][k0];
            bf16x8 b1 = *(const bf16x8*)&h1h[16 + ln][k0];
            acc0 = __builtin_amdgcn_mfma_f32_16x16x32_bf16(av, b0, acc0, 0, 0, 0);
            acc1 = __builtin_amdgcn_mfma_f32_16x16x32_bf16(av, b1, acc1, 0, 0, 0);
        }
        const int r0 = wv * 16 + kg * 4;
        float4 fb4 = *(const float4*)(f2b + r0);
        float4 g24 = *(const float4*)(g2 + r0);
        #pragma unroll
        for (int reg = 0; reg < 4; ++reg) {
            const int row = r0 + reg;
            out[row * HW + pix0 + ln]      = xres[row][ln]
                                           + (&g24.x)[reg] * (acc0[reg] + (&fb4.x)[reg]);
            out[row * HW + pix0 + 16 + ln] = xres[row][16 + ln]
                                           + (&g24.x)[reg] * (acc1[reg] + (&fb4.x)[reg]);
        }
    }
}

extern "C" void kernel_launch(void* const* d_in, const int* in_sizes, int n_in,
                              void* d_out, int out_size, void* d_ws, size_t ws_size,
                              hipStream_t stream) {
    (void)in_sizes; (void)n_in; (void)out_size; (void)ws_size;
    const float* x      = (const float*)d_in[0];
    const float* n1w    = (const float*)d_in[1];
    const float* n1b    = (const float*)d_in[2];
    const float* qkvw   = (const float*)d_in[3];
    const float* qkvb   = (const float*)d_in[4];
    const float* qnw    = (const float*)d_in[5];
    const float* qnb    = (const float*)d_in[6];
    const float* knw    = (const float*)d_in[7];
    const float* knb    = (const float*)d_in[8];
    const float* pw     = (const float*)d_in[9];
    const float* pb     = (const float*)d_in[10];
    const float* g1     = (const float*)d_in[11];
    const float* n2w    = (const float*)d_in[12];
    const float* n2b    = (const float*)d_in[13];
    const float* f1w    = (const float*)d_in[14];
    const float* f1b    = (const float*)d_in[15];
    const float* mnw    = (const float*)d_in[16];
    const float* mnb    = (const float*)d_in[17];
    const float* f2w    = (const float*)d_in[18];
    const float* f2b    = (const float*)d_in[19];
    const float* g2     = (const float*)d_in[20];
    float* out = (float*)d_out;

    float* ws = (float*)d_ws;
    const size_t CHW = (size_t)CC * HW;   // 1,048,576 floats
    float* qo   = ws;
    float* ko   = ws + CHW;
    float* vo   = ws + 2 * CHW;
    float* oatt = ws + 3 * CHW;
    unsigned short* wsh = (unsigned short*)(ws + 4 * CHW);
    unsigned short* pwh = wsh;            // 4096
    unsigned short* f1h = wsh + 4096;     // 8192
    unsigned short* f2h = wsh + 12288;    // 8192

    k_ln_qkv<<<dim3(HW / 32), dim3(256), 0, stream>>>(
        x, n1w, n1b, qkvw, qkvb, qnw, qnb, knw, knb, qo, ko, vo);
    k_attn<<<dim3(4, 16, 8), dim3(256), 0, stream>>>(
        qo, ko, vo, oatt, pw, f1w, f2w, pwh, f1h, f2h);
    k_mlp<<<dim3(HW / 32), dim3(256), 0, stream>>>(
        x, oatt, pwh, pb, g1, n2w, n2b, f1h, f1b, mnw, mnb, f2h, f2b, g2, out);
}

// Round 9
// 128.565 us; speedup vs baseline: 1.9813x; 1.0239x over previous
//
#include <hip/hip_runtime.h>
#include <math.h>

#define HW 16384
#define CC 64
#define HID 128
#define EPSV 1e-5f
#define ROW 36     // padded LDS row for 32-pixel fp32 tiles
#define QROW 197   // padded per-pixel row for qkv fp32 staging (192 + 5, odd)
#define HDSTR 131072    // per-head stride: 32*32*16*8 floats

typedef __attribute__((ext_vector_type(8))) short bf16x8;   // 8 bf16 = 4 VGPRs
typedef __attribute__((ext_vector_type(4))) float f32x4v;   // MFMA accumulator

__device__ __forceinline__ unsigned short f2bf(float f) {   // RNE fp32->bf16
    unsigned u = __float_as_uint(f);
    u += 0x7FFFu + ((u >> 16) & 1u);
    return (unsigned short)(u >> 16);
}
__device__ __forceinline__ unsigned pack2bf(float a, float b) {
    return (unsigned)f2bf(a) | ((unsigned)f2bf(b) << 16);
}

// q/k/v layout: [head][(hs*32+ws)*16 + sub][8], sub = (h&3)*4 + (w&3)

// ---------------- Kernel A: ln1 -> qkv via MFMA -> q/k LN -> ws (r8-verified) ----------------
__global__ __launch_bounds__(256) void k_ln_qkv(
    const float* __restrict__ x,
    const float* __restrict__ n1w, const float* __restrict__ n1b,
    const float* __restrict__ qkvw, const float* __restrict__ qkvb,
    const float* __restrict__ qnw, const float* __restrict__ qnb,
    const float* __restrict__ knw, const float* __restrict__ knb,
    float* __restrict__ qo, float* __restrict__ ko, float* __restrict__ vo)
{
    __shared__ __align__(16) float xs[CC][ROW];              // fp32 x tile [chan][px]
    __shared__ __align__(16) unsigned short xh[32][72];      // ln1(x) bf16 [px][chan]
    __shared__ __align__(16) unsigned short wh[192][72];     // qkvw bf16 [out][k]
    __shared__ __align__(16) float qk[32][QROW];             // qkv out fp32 [px][out]
    __shared__ __align__(16) float mu1[32], rs1[32], muq[32], rsq[32], muk[32], rsk[32];

    const int t = threadIdx.x;
    const int pix0 = blockIdx.x * 32;
    const int wv = t >> 6;      // wave 0..3
    const int l = t & 63;
    const int ln = l & 15;      // frag col (px) / A-row within 16-stripe
    const int kg = l >> 4;      // frag k-group

    {
        const int c = t >> 2, pxq = (t & 3) * 8;
        *(float4*)&xs[c][pxq]     = *(const float4*)(x + c * HW + pix0 + pxq);
        *(float4*)&xs[c][pxq + 4] = *(const float4*)(x + c * HW + pix0 + pxq + 4);
    }
    #pragma unroll
    for (int i = 0; i < 12; ++i) {
        const int f = i * 256 + t;
        const int row = f >> 4;
        const int k4 = (f & 15) * 4;
        float4 wv4 = *(const float4*)(qkvw + row * 64 + k4);
        *(unsigned*)&wh[row][k4]     = pack2bf(wv4.x, wv4.y);
        *(unsigned*)&wh[row][k4 + 2] = pack2bf(wv4.z, wv4.w);
    }
    __syncthreads();

    if (t < 128) {
        const int px = ((t >> 6) << 4) + (t & 15);
        const int part = (t & 63) >> 4;
        float s = 0.f, ss = 0.f;
        #pragma unroll
        for (int i = 0; i < 16; ++i) { float v = xs[part * 16 + i][px]; s += v; ss += v * v; }
        s += __shfl_xor(s, 16); ss += __shfl_xor(ss, 16);
        s += __shfl_xor(s, 32); ss += __shfl_xor(ss, 32);
        if (part == 0) {
            float m = s * (1.f / CC);
            mu1[px] = m;
            rs1[px] = rsqrtf(ss * (1.f / CC) - m * m + EPSV);
        }
    }
    __syncthreads();

    {
        const int c2 = (t & 31) * 2, px0 = (t >> 5) * 4;
        const float w0 = n1w[c2], b0 = n1b[c2];
        const float w1 = n1w[c2 + 1], b1 = n1b[c2 + 1];
        float4 va = *(float4*)&xs[c2][px0];
        float4 vb = *(float4*)&xs[c2 + 1][px0];
        float4 m4 = *(float4*)&mu1[px0];
        float4 r4 = *(float4*)&rs1[px0];
        #pragma unroll
        for (int i = 0; i < 4; ++i) {
            float f0 = ((&va.x)[i] - (&m4.x)[i]) * (&r4.x)[i] * w0 + b0;
            float f1 = ((&vb.x)[i] - (&m4.x)[i]) * (&r4.x)[i] * w1 + b1;
            *(unsigned*)&xh[px0 + i][c2] = pack2bf(f0, f1);
        }
    }
    __syncthreads();

    {
        f32x4v acc[3][2];
        #pragma unroll
        for (int mt = 0; mt < 3; ++mt) {
            acc[mt][0] = (f32x4v){0.f, 0.f, 0.f, 0.f};
            acc[mt][1] = (f32x4v){0.f, 0.f, 0.f, 0.f};
        }
        const int mbase = wv * 48;
        #pragma unroll
        for (int kk = 0; kk < 64; kk += 32) {
            const int k0 = kk + kg * 8;
            bf16x8 b0 = *(const bf16x8*)&xh[ln][k0];
            bf16x8 b1 = *(const bf16x8*)&xh[16 + ln][k0];
            #pragma unroll
            for (int mt = 0; mt < 3; ++mt) {
                bf16x8 av = *(const bf16x8*)&wh[mbase + mt * 16 + ln][k0];
                acc[mt][0] = __builtin_amdgcn_mfma_f32_16x16x32_bf16(av, b0, acc[mt][0], 0, 0, 0);
                acc[mt][1] = __builtin_amdgcn_mfma_f32_16x16x32_bf16(av, b1, acc[mt][1], 0, 0, 0);
            }
        }
        #pragma unroll
        for (int mt = 0; mt < 3; ++mt) {
            const int r0 = mbase + mt * 16 + kg * 4;
            float4 qb4 = *(const float4*)(qkvb + r0);
            #pragma unroll
            for (int reg = 0; reg < 4; ++reg) {
                qk[ln][r0 + reg]      = acc[mt][0][reg] + (&qb4.x)[reg];
                qk[16 + ln][r0 + reg] = acc[mt][1][reg] + (&qb4.x)[reg];
            }
        }
    }
    __syncthreads();

    if (t < 128) {
        const int px = ((t >> 6) << 4) + (t & 15);
        const int part = (t & 63) >> 4;
        float s = 0.f, ss = 0.f;
        #pragma unroll
        for (int i = 0; i < 16; ++i) { float v = qk[px][part * 16 + i]; s += v; ss += v * v; }
        s += __shfl_xor(s, 16); ss += __shfl_xor(ss, 16);
        s += __shfl_xor(s, 32); ss += __shfl_xor(ss, 32);
        if (part == 0) {
            float m = s * (1.f / CC);
            muq[px] = m;
            rsq[px] = rsqrtf(ss * (1.f / CC) - m * m + EPSV);
        }
    } else {
        const int t2 = t - 128;
        const int px = ((t2 >> 6) << 4) + (t2 & 15);
        const int part = (t2 & 63) >> 4;
        float s = 0.f, ss = 0.f;
        #pragma unroll
        for (int i = 0; i < 16; ++i) { float v = qk[px][CC + part * 16 + i]; s += v; ss += v * v; }
        s += __shfl_xor(s, 16); ss += __shfl_xor(ss, 16);
        s += __shfl_xor(s, 32); ss += __shfl_xor(ss, 32);
        if (part == 0) {
            float m = s * (1.f / CC);
            muk[px] = m;
            rsk[px] = rsqrtf(ss * (1.f / CC) - m * m + EPSV);
        }
    }
    __syncthreads();

    #pragma unroll
    for (int pass = 0; pass < 2; ++pass) {
        const int px = (t >> 4) + pass * 16;
        const int cg = t & 15;
        const int c = cg * 4;
        const int hd = cg >> 1;
        const int d4 = (cg & 1) * 4;
        const int pixel = pix0 + px;
        const int h = pixel >> 7, w = pixel & 127;
        const int pos = ((h >> 2) * 32 + (w >> 2)) * 16 + (h & 3) * 4 + (w & 3);
        const int gbase = hd * HDSTR + pos * 8 + d4;

        const float mq = muq[px], rq = rsq[px];
        float4 qv = *(float4*)&qk[px][c];
        float4 qw = *(const float4*)(qnw + c);
        float4 qb = *(const float4*)(qnb + c);
        qv.x = (qv.x - mq) * rq * qw.x + qb.x;
        qv.y = (qv.y - mq) * rq * qw.y + qb.y;
        qv.z = (qv.z - mq) * rq * qw.z + qb.z;
        qv.w = (qv.w - mq) * rq * qw.w + qb.w;
        *(float4*)(qo + gbase) = qv;

        const float mk = muk[px], rk = rsk[px];
        float4 kv = *(float4*)&qk[px][CC + c];
        float4 kw = *(const float4*)(knw + c);
        float4 kb = *(const float4*)(knb + c);
        kv.x = (kv.x - mk) * rk * kw.x + kb.x;
        kv.y = (kv.y - mk) * rk * kw.y + kb.y;
        kv.z = (kv.z - mk) * rk * kw.z + kb.z;
        kv.w = (kv.w - mk) * rk * kw.w + kb.w;
        *(float4*)(ko + gbase) = kv;

        float4 vv = *(float4*)&qk[px][2 * CC + c];
        *(float4*)(vo + gbase) = vv;
    }
}

// ---------------- Kernel B: NAT, 512 threads, neighbor-split 2-way + LDS merge ----------------
// Threads 0-255 (waves 0-3) handle neighbor rows i=0..3; threads 256-511 rows i=4..7
// (same q-pixel). Each half runs two-pass softmax on its 32 neighbors with its own
// max; halves merge via rescale L = l0*e^(m0-M) + l1*e^(m1-M). half is wave-uniform.
__global__ __launch_bounds__(512, 4) void k_attn(
    const float* __restrict__ q, const float* __restrict__ k, const float* __restrict__ v,
    float* __restrict__ o,
    const float* __restrict__ pw, const float* __restrict__ f1w, const float* __restrict__ f2w,
    unsigned short* __restrict__ pwh, unsigned short* __restrict__ f1h,
    unsigned short* __restrict__ f2h)
{
    __shared__ __align__(16) float kt[4][15][33][2];
    __shared__ __align__(16) float vt[4][15][33][2];
    __shared__ __align__(16) float pm[2][256];
    __shared__ __align__(16) float pl[2][256];
    __shared__ __align__(16) float pacc[2][256][8];

    const int t = threadIdx.x;
    const int half = t >> 8;        // 0 or 1 (wave-uniform)
    const int tt = t & 255;
    const int band = blockIdx.x;
    const int sub  = blockIdx.y;
    const int head = blockIdx.z;
    const int hs0 = band * 8;

    // one-shot bf16 conversion of C's weights
    {
        const int gtid = ((blockIdx.z * 16 + blockIdx.y) * 4 + blockIdx.x) * 512 + t;
        if (gtid < 4096)        pwh[gtid] = f2bf(pw[gtid]);
        else if (gtid < 12288)  f1h[gtid - 4096] = f2bf(f1w[gtid - 4096]);
        else if (gtid < 20480)  f2h[gtid - 12288] = f2bf(f2w[gtid - 12288]);
    }

    const float* kb = k + head * HDSTR;
    const float* vb = v + head * HDSTR;

    // stage k/v subgrid rows hs0-4 .. hs0+10 (clamped): 960 float4-pairs over 512 thr
    for (int idx = t; idx < 960; idx += 512) {
        const int row = idx >> 6;
        const int rem = idx & 63;
        const int wsc = rem >> 1;
        const int dh = rem & 1;
        int gr = hs0 - 4 + row;
        gr = gr < 0 ? 0 : (gr > 31 ? 31 : gr);
        const int gaddr = ((gr * 32 + wsc) * 16 + sub) * 8 + dh * 4;
        const float4 kv4 = *(const float4*)(kb + gaddr);
        const float4 vv4 = *(const float4*)(vb + gaddr);
        const int dp = dh * 2;
        kt[dp][row][wsc][0] = kv4.x;     kt[dp][row][wsc][1] = kv4.y;
        kt[dp + 1][row][wsc][0] = kv4.z; kt[dp + 1][row][wsc][1] = kv4.w;
        vt[dp][row][wsc][0] = vv4.x;     vt[dp][row][wsc][1] = vv4.y;
        vt[dp + 1][row][wsc][0] = vv4.z; vt[dp + 1][row][wsc][1] = vv4.w;
    }

    const int r = tt >> 5;        // 0..7
    const int wsc = tt & 31;      // 0..31
    const int hs = hs0 + r;

    const float* qp = q + head * HDSTR + ((hs * 32 + wsc) * 16 + sub) * 8;
    const float4 q0 = *(const float4*)qp;
    const float4 q1 = *(const float4*)(qp + 4);
    const float scale = 0.35355339059327373f;   // 8^-0.5

    __syncthreads();

    // ---- pass 1: this half's 32 scores into registers; 4-way parallel max ----
    float s[32];
    float mx0 = -1e30f, mx1 = -1e30f, mx2 = -1e30f, mx3 = -1e30f;
    #pragma unroll
    for (int ii = 0; ii < 4; ++ii) {
        const int i = half * 4 + ii;
        const int lr = r + i;                               // LDS row 0..14
        const bool vh = (unsigned)(hs + i - 4) < 32u;
        #pragma unroll
        for (int j = 0; j < 8; ++j) {
            const int cs = wsc + j - 4;
            const bool valid = vh && ((unsigned)cs < 32u);
            const int cc = cs < 0 ? 0 : (cs > 31 ? 31 : cs);
            const float2 kA = *(const float2*)&kt[0][lr][cc][0];
            const float2 kB = *(const float2*)&kt[1][lr][cc][0];
            const float2 kC = *(const float2*)&kt[2][lr][cc][0];
            const float2 kD = *(const float2*)&kt[3][lr][cc][0];
            float sv = q0.x * kA.x + q0.y * kA.y + q0.z * kB.x + q0.w * kB.y
                     + q1.x * kC.x + q1.y * kC.y + q1.z * kD.x + q1.w * kD.y;
            sv *= scale;
            sv = valid ? sv : -INFINITY;
            s[ii * 8 + j] = sv;
            if ((j & 3) == 0)      mx0 = fmaxf(mx0, sv);
            else if ((j & 3) == 1) mx1 = fmaxf(mx1, sv);
            else if ((j & 3) == 2) mx2 = fmaxf(mx2, sv);
            else                   mx3 = fmaxf(mx3, sv);
        }
    }
    const float mxh = fmaxf(fmaxf(mx0, mx1), fmaxf(mx2, mx3));

    // ---- pass 2: exp + PV accumulate (this half's max; masked taps give p=0) ----
    float l = 0.f;
    float a0 = 0.f, a1 = 0.f, a2 = 0.f, a3 = 0.f, a4 = 0.f, a5 = 0.f, a6 = 0.f, a7 = 0.f;
    #pragma unroll
    for (int ii = 0; ii < 4; ++ii) {
        const int i = half * 4 + ii;
        const int lr = r + i;
        #pragma unroll
        for (int j = 0; j < 8; ++j) {
            const int cs = wsc + j - 4;
            const int cc = cs < 0 ? 0 : (cs > 31 ? 31 : cs);
            const float p = __expf(s[ii * 8 + j] - mxh);
            const float2 vA = *(const float2*)&vt[0][lr][cc][0];
            const float2 vB = *(const float2*)&vt[1][lr][cc][0];
            const float2 vC = *(const float2*)&vt[2][lr][cc][0];
            const float2 vD = *(const float2*)&vt[3][lr][cc][0];
            l += p;
            a0 += p * vA.x;  a1 += p * vA.y;
            a2 += p * vB.x;  a3 += p * vB.y;
            a4 += p * vC.x;  a5 += p * vC.y;
            a6 += p * vD.x;  a7 += p * vD.y;
        }
    }

    // ---- publish partials, merge across halves ----
    pm[half][tt] = mxh;
    pl[half][tt] = l;
    float4 own0 = {a0, a1, a2, a3};
    float4 own1 = {a4, a5, a6, a7};
    *(float4*)&pacc[half][tt][0] = own0;
    *(float4*)&pacc[half][tt][4] = own1;
    __syncthreads();

    const int oth = half ^ 1;
    const float m_o = pm[oth][tt];
    const float l_o = pl[oth][tt];
    // each half only needs the other's float4 matching its own output half
    const float4 po = (half == 0) ? *(const float4*)&pacc[oth][tt][0]
                                  : *(const float4*)&pacc[oth][tt][4];
    const float4 ow = (half == 0) ? own0 : own1;

    const float M = fmaxf(mxh, m_o);
    const float eo = __expf(mxh - M);
    const float eh = __expf(m_o - M);
    const float inv = 1.f / (l * eo + l_o * eh);

    const int a = sub >> 2, b = sub & 3;
    const int h = hs * 4 + a, w = wsc * 4 + b;
    float* op = o + (h * 128 + w) * 64 + head * 8 + half * 4;
    float4 res = {(ow.x * eo + po.x * eh) * inv, (ow.y * eo + po.y * eh) * inv,
                  (ow.z * eo + po.z * eh) * inv, (ow.w * eo + po.w * eh) * inv};
    *(float4*)op = res;
}

// ---------------- Kernel C: MFMA proj/fc1/fc2 + VALU LayerNorms (r7/r8-verified) ----------------
__global__ __launch_bounds__(256) void k_mlp(
    const float* __restrict__ x, const float* __restrict__ oatt,
    const unsigned short* __restrict__ pwh, const float* __restrict__ pb,
    const float* __restrict__ g1,
    const float* __restrict__ n2w, const float* __restrict__ n2b,
    const unsigned short* __restrict__ f1h, const float* __restrict__ f1b,
    const float* __restrict__ mnw, const float* __restrict__ mnb,
    const unsigned short* __restrict__ f2h, const float* __restrict__ f2b,
    const float* __restrict__ g2,
    float* __restrict__ out)
{
    __shared__ __align__(16) float xres[CC][ROW];
    __shared__ __align__(16) unsigned short oh[32][72];
    __shared__ __align__(16) unsigned short tbh[32][72];
    __shared__ __align__(16) float h1[HID][ROW];
    __shared__ __align__(16) unsigned short h1h[32][136];
    __shared__ __align__(16) float mu[32], rs[32];

    const int t = threadIdx.x;
    const int pix0 = blockIdx.x * 32;
    const int wv = t >> 6;
    const int l = t & 63;
    const int ln = l & 15;
    const int kg = l >> 4;

    {
        const int c = t >> 2, pxq = (t & 3) * 8;
        *(float4*)&xres[c][pxq]     = *(const float4*)(x + c * HW + pix0 + pxq);
        *(float4*)&xres[c][pxq + 4] = *(const float4*)(x + c * HW + pix0 + pxq + 4);
    }
    #pragma unroll
    for (int pass = 0; pass < 2; ++pass) {
        const int px = (t >> 4) + pass * 16, cg = (t & 15) * 4;
        float4 ov = *(const float4*)(oatt + (pix0 + px) * CC + cg);
        *(unsigned*)&oh[px][cg]     = pack2bf(ov.x, ov.y);
        *(unsigned*)&oh[px][cg + 2] = pack2bf(ov.z, ov.w);
    }
    __syncthreads();

    {
        f32x4v acc0 = {0.f, 0.f, 0.f, 0.f}, acc1 = {0.f, 0.f, 0.f, 0.f};
        const int m = wv * 16 + ln;
        #pragma unroll
        for (int kk = 0; kk < 64; kk += 32) {
            const int k0 = kk + kg * 8;
            bf16x8 av = *(const bf16x8*)(pwh + m * 64 + k0);
            bf16x8 b0 = *(const bf16x8*)&oh[ln][k0];
            bf16x8 b1 = *(const bf16x8*)&oh[16 + ln][k0];
            acc0 = __builtin_amdgcn_mfma_f32_16x16x32_bf16(av, b0, acc0, 0, 0, 0);
            acc1 = __builtin_amdgcn_mfma_f32_16x16x32_bf16(av, b1, acc1, 0, 0, 0);
        }
        const int r0 = wv * 16 + kg * 4;
        float4 pb4 = *(const float4*)(pb + r0);
        float4 g14 = *(const float4*)(g1 + r0);
        #pragma unroll
        for (int reg = 0; reg < 4; ++reg) {
            const int row = r0 + reg;
            xres[row][ln]      += (&g14.x)[reg] * (acc0[reg] + (&pb4.x)[reg]);
            xres[row][16 + ln] += (&g14.x)[reg] * (acc1[reg] + (&pb4.x)[reg]);
        }
    }
    __syncthreads();

    if (t < 128) {
        const int px = ((t >> 6) << 4) + (t & 15);
        const int part = (t & 63) >> 4;
        float s = 0.f, ss = 0.f;
        #pragma unroll
        for (int i = 0; i < 16; ++i) { float v = xres[part * 16 + i][px]; s += v; ss += v * v; }
        s += __shfl_xor(s, 16); ss += __shfl_xor(ss, 16);
        s += __shfl_xor(s, 32); ss += __shfl_xor(ss, 32);
        if (part == 0) {
            float m = s * (1.f / CC);
            mu[px] = m;
            rs[px] = rsqrtf(ss * (1.f / CC) - m * m + EPSV);
        }
    }
    __syncthreads();

    {
        const int c2 = (t & 31) * 2, px0 = (t >> 5) * 4;
        const float w0 = n2w[c2], b0 = n2b[c2];
        const float w1 = n2w[c2 + 1], b1 = n2b[c2 + 1];
        float4 va = *(float4*)&xres[c2][px0];
        float4 vb = *(float4*)&xres[c2 + 1][px0];
        float4 m4 = *(float4*)&mu[px0];
        float4 r4 = *(float4*)&rs[px0];
        #pragma unroll
        for (int i = 0; i < 4; ++i) {
            float f0 = ((&va.x)[i] - (&m4.x)[i]) * (&r4.x)[i] * w0 + b0;
            float f1 = ((&vb.x)[i] - (&m4.x)[i]) * (&r4.x)[i] * w1 + b1;
            *(unsigned*)&tbh[px0 + i][c2] = pack2bf(f0, f1);
        }
    }
    __syncthreads();

    {
        f32x4v a00 = {0.f,0.f,0.f,0.f}, a01 = {0.f,0.f,0.f,0.f};
        f32x4v a10 = {0.f,0.f,0.f,0.f}, a11 = {0.f,0.f,0.f,0.f};
        const int m0 = wv * 32 + ln;
        #pragma unroll
        for (int kk = 0; kk < 64; kk += 32) {
            const int k0 = kk + kg * 8;
            bf16x8 av0 = *(const bf16x8*)(f1h + m0 * 64 + k0);
            bf16x8 av1 = *(const bf16x8*)(f1h + (m0 + 16) * 64 + k0);
            bf16x8 b0 = *(const bf16x8*)&tbh[ln][k0];
            bf16x8 b1 = *(const bf16x8*)&tbh[16 + ln][k0];
            a00 = __builtin_amdgcn_mfma_f32_16x16x32_bf16(av0, b0, a00, 0, 0, 0);
            a01 = __builtin_amdgcn_mfma_f32_16x16x32_bf16(av0, b1, a01, 0, 0, 0);
            a10 = __builtin_amdgcn_mfma_f32_16x16x32_bf16(av1, b0, a10, 0, 0, 0);
            a11 = __builtin_amdgcn_mfma_f32_16x16x32_bf16(av1, b1, a11, 0, 0, 0);
        }
        const int r0 = wv * 32 + kg * 4;
        float4 fb0 = *(const float4*)(f1b + r0);
        float4 fb1 = *(const float4*)(f1b + r0 + 16);
        #pragma unroll
        for (int reg = 0; reg < 4; ++reg) {
            h1[r0 + reg][ln]           = a00[reg] + (&fb0.x)[reg];
            h1[r0 + reg][16 + ln]      = a01[reg] + (&fb0.x)[reg];
            h1[r0 + 16 + reg][ln]      = a10[reg] + (&fb1.x)[reg];
            h1[r0 + 16 + reg][16 + ln] = a11[reg] + (&fb1.x)[reg];
        }
    }
    __syncthreads();

    if (t < 128) {
        const int px = ((t >> 6) << 4) + (t & 15);
        const int part = (t & 63) >> 4;
        float s = 0.f, ss = 0.f;
        #pragma unroll
        for (int i = 0; i < 32; ++i) { float v = h1[part * 32 + i][px]; s += v; ss += v * v; }
        s += __shfl_xor(s, 16); ss += __shfl_xor(ss, 16);
        s += __shfl_xor(s, 32); ss += __shfl_xor(ss, 32);
        if (part == 0) {
            float m = s * (1.f / HID);
            mu[px] = m;
            rs[px] = rsqrtf(ss * (1.f / HID) - m * m + EPSV);
        }
    }
    __syncthreads();

    {
        const int c2 = (t & 63) * 2, pxm = (t >> 6) * 8;
        const float w0 = mnw[c2], b0 = mnb[c2];
        const float w1 = mnw[c2 + 1], b1 = mnb[c2 + 1];
        #pragma unroll
        for (int qq = 0; qq < 2; ++qq) {
            float4 va = *(float4*)&h1[c2][pxm + qq * 4];
            float4 vb = *(float4*)&h1[c2 + 1][pxm + qq * 4];
            float4 m4 = *(float4*)&mu[pxm + qq * 4];
            float4 r4 = *(float4*)&rs[pxm + qq * 4];
            #pragma unroll
            for (int i = 0; i < 4; ++i) {
                float h0 = ((&va.x)[i] - (&m4.x)[i]) * (&r4.x)[i] * w0 + b0;
                float h1v = ((&vb.x)[i] - (&m4.x)[i]) * (&r4.x)[i] * w1 + b1;
                h0 = h0 / (1.f + __expf(-h0));
                h1v = h1v / (1.f + __expf(-h1v));
                *(unsigned*)&h1h[pxm + qq * 4 + i][c2] = pack2bf(h0, h1v);
            }
        }
    }
    __syncthreads();

    {
        f32x4v acc0 = {0.f, 0.f, 0.f, 0.f}, acc1 = {0.f, 0.f, 0.f, 0.f};
        const int m = wv * 16 + ln;
        #pragma unroll
        for (int kk = 0; kk < 128; kk += 32) {
            const int k0 = kk + kg * 8;
            bf16x8 av = *(const bf16x8*)(f2h + m * 128 + k0);
            bf16x8 b0 = *(const bf16x8*)&h1h[ln][k0];
            bf16x8 b1 = *(const bf16x8*)&h1h[16 + ln][k0];
            acc0 = __builtin_amdgcn_mfma_f32_16x16x32_bf16(av, b0, acc0, 0, 0, 0);
            acc1 = __builtin_amdgcn_mfma_f32_16x16x32_bf16(av, b1, acc1, 0, 0, 0);
        }
        const int r0 = wv * 16 + kg * 4;
        float4 fb4 = *(const float4*)(f2b + r0);
        float4 g24 = *(const float4*)(g2 + r0);
        #pragma unroll
        for (int reg = 0; reg < 4; ++reg) {
            const int row = r0 + reg;
            out[row * HW + pix0 + ln]      = xres[row][ln]
                                           + (&g24.x)[reg] * (acc0[reg] + (&fb4.x)[reg]);
            out[row * HW + pix0 + 16 + ln] = xres[row][16 + ln]
                                           + (&g24.x)[reg] * (acc1[reg] + (&fb4.x)[reg]);
        }
    }
}

extern "C" void kernel_launch(void* const* d_in, const int* in_sizes, int n_in,
                              void* d_out, int out_size, void* d_ws, size_t ws_size,
                              hipStream_t stream) {
    (void)in_sizes; (void)n_in; (void)out_size; (void)ws_size;
    const float* x      = (const float*)d_in[0];
    const float* n1w    = (const float*)d_in[1];
    const float* n1b    = (const float*)d_in[2];
    const float* qkvw   = (const float*)d_in[3];
    const float* qkvb   = (const float*)d_in[4];
    const float* qnw    = (const float*)d_in[5];
    const float* qnb    = (const float*)d_in[6];
    const float* knw    = (const float*)d_in[7];
    const float* knb    = (const float*)d_in[8];
    const float* pw     = (const float*)d_in[9];
    const float* pb     = (const float*)d_in[10];
    const float* g1     = (const float*)d_in[11];
    const float* n2w    = (const float*)d_in[12];
    const float* n2b    = (const float*)d_in[13];
    const float* f1w    = (const float*)d_in[14];
    const float* f1b    = (const float*)d_in[15];
    const float* mnw    = (const float*)d_in[16];
    const float* mnb    = (const float*)d_in[17];
    const float* f2w    = (const float*)d_in[18];
    const float* f2b    = (const float*)d_in[19];
    const float* g2     = (const float*)d_in[20];
    float* out = (float*)d_out;

    float* ws = (float*)d_ws;
    const size_t CHW = (size_t)CC * HW;   // 1,048,576 floats
    float* qo   = ws;
    float* ko   = ws + CHW;
    float* vo   = ws + 2 * CHW;
    float* oatt = ws + 3 * CHW;
    unsigned short* wsh = (unsigned short*)(ws + 4 * CHW);
    unsigned short* pwh = wsh;            // 4096
    unsigned short* f1h = wsh + 4096;     // 8192
    unsigned short* f2h = wsh + 12288;    // 8192

    k_ln_qkv<<<dim3(HW / 32), dim3(256), 0, stream>>>(
        x, n1w, n1b, qkvw, qkvb, qnw, qnb, knw, knb, qo, ko, vo);
    k_attn<<<dim3(4, 16, 8), dim3(512), 0, stream>>>(
        qo, ko, vo, oatt, pw, f1w, f2w, pwh, f1h, f2h);
    k_mlp<<<dim3(HW / 32), dim3(256), 0, stream>>>(
        x, oatt, pwh, pb, g1, n2w, n2b, f1h, f1b, mnw, mnb, f2h, f2b, g2, out);
}